// Round 1
// baseline (2491.036 us; speedup 1.0000x reference)
//
#include <hip/hip_runtime.h>

#define BSZ 8
#define TLEN 1024
#define DIN 32
#define DM 64
#define DI 128
#define DS 32
#define NTOK (BSZ*TLEN)

__device__ __forceinline__ float siluf(float x) { return x / (1.f + expf(-x)); }
__device__ __forceinline__ float softplusf(float x) { return (x > 20.f) ? x : log1pf(expf(x)); }

// ---------------- per-token MLP: relu(x@W1+b1)@W2+b2 ----------------
template<int IN, int H, int OUT>
__global__ __launch_bounds__(64) void mlp_kernel(
    const float* __restrict__ x, const float* __restrict__ W1, const float* __restrict__ b1,
    const float* __restrict__ W2, const float* __restrict__ b2, float* __restrict__ out, int ntok)
{
  __shared__ float sW1[IN*H], sW2[H*OUT], sb1[H], sb2[OUT];
  for (int i = threadIdx.x; i < IN*H;  i += blockDim.x) sW1[i] = W1[i];
  for (int i = threadIdx.x; i < H*OUT; i += blockDim.x) sW2[i] = W2[i];
  for (int i = threadIdx.x; i < H;     i += blockDim.x) sb1[i] = b1[i];
  for (int i = threadIdx.x; i < OUT;   i += blockDim.x) sb2[i] = b2[i];
  __syncthreads();
  int t = blockIdx.x * blockDim.x + threadIdx.x;
  if (t >= ntok) return;
  float xr[IN];
  #pragma unroll
  for (int i = 0; i < IN; i++) xr[i] = x[t*IN + i];
  float acc[OUT];
  #pragma unroll
  for (int o = 0; o < OUT; o++) acc[o] = sb2[o];
  for (int j = 0; j < H; j++) {
    float hj = sb1[j];
    #pragma unroll
    for (int i = 0; i < IN; i++) hj = fmaf(xr[i], sW1[i*H + j], hj);
    hj = fmaxf(hj, 0.f);
    #pragma unroll
    for (int o = 0; o < OUT; o++) acc[o] = fmaf(hj, sW2[j*OUT + o], acc[o]);
  }
  #pragma unroll
  for (int o = 0; o < OUT; o++) out[t*OUT + o] = acc[o];
}

// ---------------- window assembly: cur[b,t] = (t+p<T) ? z[b,t+p] : predz[b, t+p-T] ----------------
__global__ __launch_bounds__(256) void window_kernel(
    const float* __restrict__ z, const float* __restrict__ predz, float* __restrict__ cur, int shift)
{
  int idx = blockIdx.x*256 + threadIdx.x;
  if (idx >= BSZ*TLEN*DM) return;
  int c = idx & (DM-1);
  int t = (idx / DM) & (TLEN-1);
  int b = idx / (DM*TLEN);
  int st = t + shift;
  cur[idx] = (st < TLEN) ? z[(b*TLEN + st)*DM + c] : predz[(b*4 + (st - TLEN))*DM + c];
}

// ---------------- pre: xz GEMM + causal conv + silu + xproj + dt ----------------
// 32 tokens per workgroup (plus 3-token halo for the conv), one batch per tile.
__global__ __launch_bounds__(256) void pre_kernel(
    const float* __restrict__ inbuf,
    const float* __restrict__ Win, const float* __restrict__ Wconv, const float* __restrict__ bconv,
    const float* __restrict__ Wxproj, const float* __restrict__ Wdt, const float* __restrict__ bdt,
    float* __restrict__ xibuf, float* __restrict__ resgbuf,
    float* __restrict__ dtbuf, float* __restrict__ dtxbuf,
    float* __restrict__ Bbuf, float* __restrict__ Cbuf)
{
  __shared__ float s_in[35*64];     // input rows (tokens t0-3 .. t0+31)
  __shared__ float s_big[35*256];   // xz; later reused for Wxproj (128*68 <= 35*256)
  __shared__ float s_xi[32*128];
  __shared__ float s_dtr[32*4];
  const int tid = threadIdx.x;
  const int b  = blockIdx.x >> 5;
  const int t0 = (blockIdx.x & 31) * 32;

  for (int i = tid; i < 35*64; i += 256) {
    int r = i >> 6, c = i & 63;
    int t = t0 - 3 + r;
    s_in[i] = (t >= 0) ? inbuf[(b*TLEN + t)*DM + c] : 0.f;
  }
  __syncthreads();
  // xz = in @ Win : thread tid owns column tid (of 256), loops 35 rows
  {
    float wcol[64];
    #pragma unroll
    for (int i = 0; i < 64; i++) wcol[i] = Win[i*256 + tid];
    for (int r = 0; r < 35; r++) {
      float acc = 0.f;
      #pragma unroll
      for (int i = 0; i < 64; i++) acc = fmaf(s_in[r*64 + i], wcol[i], acc);
      s_big[r*256 + tid] = acc;
    }
  }
  __syncthreads();
  // causal conv (K=4) + bias + silu on xi half; silu on res half
  for (int i = tid; i < 32*128; i += 256) {
    int tau = i >> 7, d = i & 127;
    float acc = bconv[d];
    #pragma unroll
    for (int k = 0; k < 4; k++) acc = fmaf(s_big[(tau + k)*256 + d], Wconv[d*4 + k], acc);
    float xiv = siluf(acc);
    s_xi[i] = xiv;
    int g = (b*TLEN + t0 + tau)*DI + d;
    xibuf[g] = xiv;
    float rv = s_big[(tau + 3)*256 + 128 + d];
    resgbuf[g] = siluf(rv);
  }
  __syncthreads();
  // reuse s_big for Wxproj
  for (int i = tid; i < 128*68; i += 256) s_big[i] = Wxproj[i];
  __syncthreads();
  // xdbl = xi @ Wxproj : 32 tokens x 68 cols
  for (int i = tid; i < 32*68; i += 256) {
    int tau = i / 68, c = i % 68;
    float acc = 0.f;
    for (int k = 0; k < 128; k++) acc = fmaf(s_xi[tau*128 + k], s_big[k*68 + c], acc);
    if (c < 4)        s_dtr[tau*4 + c] = acc;
    else if (c < 36)  Bbuf[(b*TLEN + t0 + tau)*DS + (c - 4)]  = acc;
    else              Cbuf[(b*TLEN + t0 + tau)*DS + (c - 36)] = acc;
  }
  __syncthreads();
  // dt = softplus(dtr @ Wdt + bdt); dtx = dt * xi
  for (int i = tid; i < 32*128; i += 256) {
    int tau = i >> 7, d = i & 127;
    float acc = bdt[d];
    #pragma unroll
    for (int r = 0; r < 4; r++) acc = fmaf(s_dtr[tau*4 + r], Wdt[r*128 + d], acc);
    float dtv = softplusf(acc);
    int g = (b*TLEN + t0 + tau)*DI + d;
    dtbuf[g] = dtv;
    dtxbuf[g] = dtv * s_xi[i];
  }
}

// ---------------- scan: h = exp(dt*A)*h + (dt*x)*B ; y = sum_s h*C ----------------
// 128 threads = 4 channels x 32 states; LDS-staged 64-step tiles.
__global__ __launch_bounds__(128) void scan_kernel(
    const float* __restrict__ dtbuf, const float* __restrict__ dtxbuf,
    const float* __restrict__ Bbuf, const float* __restrict__ Cbuf,
    const float* __restrict__ Alog, float* __restrict__ ysbuf)
{
  __shared__ float s_dt[64*4], s_dtx[64*4], s_B[64*32], s_C[64*32];
  const int tid = threadIdx.x;
  const int w = tid >> 5;          // channel within block (0..3)
  const int s = tid & 31;          // state index
  const int ch0 = blockIdx.x * 4;
  const int b  = ch0 >> 7;
  const int d0 = ch0 & 127;
  const int d  = d0 + w;
  const float A = -expf(Alog[d*DS + s]);
  float h = 0.f;
  for (int t0 = 0; t0 < TLEN; t0 += 64) {
    __syncthreads();
    for (int i = tid; i < 256; i += 128) {
      int tt = i >> 2, cc = i & 3;
      int g = (b*TLEN + t0 + tt)*DI + d0 + cc;
      s_dt[i] = dtbuf[g]; s_dtx[i] = dtxbuf[g];
    }
    for (int i = tid; i < 2048; i += 128) {
      int g = (b*TLEN + t0)*DS + i;  // contiguous block of 64 tokens x 32 states
      s_B[i] = Bbuf[g]; s_C[i] = Cbuf[g];
    }
    __syncthreads();
    #pragma unroll 4
    for (int tt = 0; tt < 64; tt++) {
      float a = __expf(s_dt[tt*4 + w] * A);
      h = fmaf(a, h, s_dtx[tt*4 + w] * s_B[tt*32 + s]);
      float p = h * s_C[tt*32 + s];
      p += __shfl_xor(p, 1);  p += __shfl_xor(p, 2);  p += __shfl_xor(p, 4);
      p += __shfl_xor(p, 8);  p += __shfl_xor(p, 16);
      if (s == 0) ysbuf[(b*TLEN + t0 + tt)*DI + d] = p;
    }
  }
}

// ---------------- post: y = (ys + xi*Dp)*silu(res); out += y @ Wout ----------------
__global__ __launch_bounds__(256) void post_kernel(
    const float* __restrict__ ysbuf, const float* __restrict__ xibuf, const float* __restrict__ resgbuf,
    const float* __restrict__ Dp, const float* __restrict__ Wout, float* __restrict__ outbuf)
{
  __shared__ float s_y[32*128];
  __shared__ float s_w[128*64];
  const int tid = threadIdx.x;
  const int b  = blockIdx.x >> 5;
  const int t0 = (blockIdx.x & 31) * 32;
  for (int i = tid; i < 128*64; i += 256) s_w[i] = Wout[i];
  for (int i = tid; i < 32*128; i += 256) {
    int g = (b*TLEN + t0)*DI + i;
    s_y[i] = (ysbuf[g] + xibuf[g]*Dp[i & 127]) * resgbuf[g];
  }
  __syncthreads();
  for (int i = tid; i < 32*64; i += 256) {
    int tau = i >> 6, c = i & 63;
    float acc = 0.f;
    for (int dd = 0; dd < 128; dd++) acc = fmaf(s_y[tau*128 + dd], s_w[dd*64 + c], acc);
    int g = (b*TLEN + t0 + tau)*DM + c;
    outbuf[g] += acc;
  }
}

// ---------------- layernorm over DM=64 per token ----------------
__global__ __launch_bounds__(256) void ln_kernel(
    const float* __restrict__ src, const float* __restrict__ g, const float* __restrict__ be,
    float* __restrict__ dst, float* __restrict__ predz, int slot, int full)
{
  int wid  = (blockIdx.x * blockDim.x + threadIdx.x) >> 6;
  int lane = threadIdx.x & 63;
  int token, b;
  if (full) { token = wid; if (token >= NTOK) return; b = token >> 10; }
  else      { b = wid; if (b >= BSZ) return; token = b*TLEN + (TLEN-1); }
  float v = src[token*DM + lane];
  float sum = v;
  #pragma unroll
  for (int m = 1; m < 64; m <<= 1) sum += __shfl_xor(sum, m);
  float mean = sum * (1.f/64.f);
  float dv = v - mean;
  float vs = dv*dv;
  #pragma unroll
  for (int m = 1; m < 64; m <<= 1) vs += __shfl_xor(vs, m);
  float var = vs * (1.f/64.f);
  float o = dv * rsqrtf(var + 1e-5f) * g[lane] + be[lane];
  if (dst) dst[token*DM + lane] = o;
  if (predz && ((token & (TLEN-1)) == TLEN-1)) predz[(b*4 + slot)*DM + lane] = o;
}

extern "C" void kernel_launch(void* const* d_in, const int* in_sizes, int n_in,
                              void* d_out, int out_size, void* d_ws, size_t ws_size,
                              hipStream_t stream)
{
  (void)in_sizes; (void)n_in; (void)out_size; (void)ws_size;
  const float* x     = (const float*)d_in[0];
  const float* We1   = (const float*)d_in[1];
  const float* be1   = (const float*)d_in[2];
  const float* We2   = (const float*)d_in[3];
  const float* be2   = (const float*)d_in[4];
  const float* Wd1   = (const float*)d_in[5];
  const float* bd1   = (const float*)d_in[6];
  const float* Wd2   = (const float*)d_in[7];
  const float* bd2   = (const float*)d_in[8];
  const float* Win   = (const float*)d_in[9];
  const float* Wconv = (const float*)d_in[10];
  const float* bconv = (const float*)d_in[11];
  const float* Wxp   = (const float*)d_in[12];
  const float* Wdt   = (const float*)d_in[13];
  const float* bdt   = (const float*)d_in[14];
  const float* Alog  = (const float*)d_in[15];
  const float* Dp    = (const float*)d_in[16];
  const float* Wout  = (const float*)d_in[17];
  const float* gamma = (const float*)d_in[18];
  const float* beta  = (const float*)d_in[19];
  // d_in[20] = pred_len = 4 (fixed by setup_inputs; not host-readable under graph capture)

  float* o      = (float*)d_out;
  float* x_rec  = o;                 // 8*1024*32
  float* x_dyn  = o + 262144;        // 8*1024*32
  float* x_pred = o + 524288;        // 8*4*32
  float* z      = o + 525312;        // 8*1024*64
  float* zdyn   = o + 1049600;       // 8*1024*64

  float* w     = (float*)d_ws;
  float* cur   = w;                  // 524288
  float* xi    = cur  + 524288;      // 1048576
  float* resg  = xi   + 1048576;     // 1048576
  float* dt    = resg + 1048576;     // 1048576
  float* dtx   = dt   + 1048576;     // 1048576
  float* Bb    = dtx  + 1048576;     // 262144
  float* Cb    = Bb   + 262144;      // 262144
  float* ys    = Cb   + 262144;      // 1048576
  float* predz = ys   + 1048576;     // 8*4*64

  // encoder: z = mlp(x)
  mlp_kernel<32,64,64><<<dim3(NTOK/64), dim3(64), 0, stream>>>(x, We1, be1, We2, be2, z, NTOK);
  // x_rec = dec(z)
  mlp_kernel<64,64,32><<<dim3(NTOK/64), dim3(64), 0, stream>>>(z, Wd1, bd1, Wd2, bd2, x_rec, NTOK);

  // 4 dynamics passes: pass 0 -> z_dyn (+ predz[0] since pred iter 0 == dyn(z)); passes 1..3 -> predz[1..3]
  for (int p = 0; p < 4; p++) {
    window_kernel<<<dim3((BSZ*TLEN*DM + 255)/256), dim3(256), 0, stream>>>(z, predz, cur, p);
    for (int i = 0; i < 2; i++) {
      const float* Win_i   = Win   + (size_t)i*64*256;
      const float* Wconv_i = Wconv + (size_t)i*128*4;
      const float* bconv_i = bconv + (size_t)i*128;
      const float* Wxp_i   = Wxp   + (size_t)i*128*68;
      const float* Wdt_i   = Wdt   + (size_t)i*4*128;
      const float* bdt_i   = bdt   + (size_t)i*128;
      const float* Alog_i  = Alog  + (size_t)i*128*32;
      const float* Dp_i    = Dp    + (size_t)i*128;
      const float* Wout_i  = Wout  + (size_t)i*128*64;
      pre_kernel <<<dim3(256), dim3(256), 0, stream>>>(cur, Win_i, Wconv_i, bconv_i, Wxp_i, Wdt_i, bdt_i,
                                                       xi, resg, dt, dtx, Bb, Cb);
      scan_kernel<<<dim3(256), dim3(128), 0, stream>>>(dt, dtx, Bb, Cb, Alog_i, ys);
      post_kernel<<<dim3(256), dim3(256), 0, stream>>>(ys, xi, resg, Dp_i, Wout_i, cur);
    }
    if (p == 0)
      ln_kernel<<<dim3(NTOK/4), dim3(256), 0, stream>>>(cur, gamma, beta, zdyn, predz, 0, 1);
    else
      ln_kernel<<<dim3(2), dim3(256), 0, stream>>>(cur, gamma, beta, (float*)nullptr, predz, p, 0);
  }

  // x_dyn = dec(z_dyn)
  mlp_kernel<64,64,32><<<dim3(NTOK/64), dim3(64), 0, stream>>>(zdyn, Wd1, bd1, Wd2, bd2, x_dyn, NTOK);
  // x_pred = dec(predz) over 8*4 = 32 tokens
  mlp_kernel<64,64,32><<<dim3(1), dim3(64), 0, stream>>>(predz, Wd1, bd1, Wd2, bd2, x_pred, 32);
}

// Round 2
// 914.411 us; speedup vs baseline: 2.7242x; 2.7242x over previous
//
#include <hip/hip_runtime.h>

#define BSZ 8
#define TLEN 1024
#define DIN 32
#define DM 64
#define DI 128
#define DS 32
#define NTOK (BSZ*TLEN)

__device__ __forceinline__ float siluf(float x) { return x / (1.f + expf(-x)); }
__device__ __forceinline__ float softplusf(float x) { return (x > 20.f) ? x : log1pf(expf(x)); }

// ---------------- per-token MLP: relu(x@W1+b1)@W2+b2 ----------------
template<int IN, int H, int OUT>
__global__ __launch_bounds__(64) void mlp_kernel(
    const float* __restrict__ x, const float* __restrict__ W1, const float* __restrict__ b1,
    const float* __restrict__ W2, const float* __restrict__ b2, float* __restrict__ out, int ntok)
{
  __shared__ float sW1[IN*H], sW2[H*OUT], sb1[H], sb2[OUT];
  for (int i = threadIdx.x; i < IN*H;  i += blockDim.x) sW1[i] = W1[i];
  for (int i = threadIdx.x; i < H*OUT; i += blockDim.x) sW2[i] = W2[i];
  for (int i = threadIdx.x; i < H;     i += blockDim.x) sb1[i] = b1[i];
  for (int i = threadIdx.x; i < OUT;   i += blockDim.x) sb2[i] = b2[i];
  __syncthreads();
  int t = blockIdx.x * blockDim.x + threadIdx.x;
  if (t >= ntok) return;
  float xr[IN];
  #pragma unroll
  for (int i = 0; i < IN; i++) xr[i] = x[t*IN + i];
  float acc[OUT];
  #pragma unroll
  for (int o = 0; o < OUT; o++) acc[o] = sb2[o];
  for (int j = 0; j < H; j++) {
    float hj = sb1[j];
    #pragma unroll
    for (int i = 0; i < IN; i++) hj = fmaf(xr[i], sW1[i*H + j], hj);
    hj = fmaxf(hj, 0.f);
    #pragma unroll
    for (int o = 0; o < OUT; o++) acc[o] = fmaf(hj, sW2[j*OUT + o], acc[o]);
  }
  #pragma unroll
  for (int o = 0; o < OUT; o++) out[t*OUT + o] = acc[o];
}

// ---------------- pre: (windowed input) -> xz GEMM + causal conv + silu + xproj + dt ----------------
__global__ __launch_bounds__(256) void pre_kernel(
    const float* __restrict__ inbuf, const float* __restrict__ zsrc, const float* __restrict__ pzsrc, int shift,
    const float* __restrict__ Win, const float* __restrict__ Wconv, const float* __restrict__ bconv,
    const float* __restrict__ Wxproj, const float* __restrict__ Wdt, const float* __restrict__ bdt,
    float* __restrict__ xibuf, float* __restrict__ resgbuf,
    float2* __restrict__ ddbuf, float* __restrict__ Bbuf, float* __restrict__ Cbuf)
{
  __shared__ float s_in[35*64];
  __shared__ float s_big[35*256];   // xz; later reused for Wxproj (128*68 <= 35*256)
  __shared__ float s_xi[32*128];
  __shared__ float s_dtr[32*4];
  const int tid = threadIdx.x;
  const int b  = blockIdx.x >> 5;
  const int t0 = (blockIdx.x & 31) * 32;

  for (int i = tid; i < 35*64; i += 256) {
    int r = i >> 6, c = i & 63;
    int tg = t0 - 3 + r;
    float v = 0.f;
    if (tg >= 0) {
      if (zsrc) {
        int st = tg + shift;
        v = (st < TLEN) ? zsrc[(b*TLEN + st)*DM + c] : pzsrc[(b*4 + (st - TLEN))*DM + c];
      } else {
        v = inbuf[(b*TLEN + tg)*DM + c];
      }
    }
    s_in[i] = v;
  }
  __syncthreads();
  {
    float wcol[64];
    #pragma unroll
    for (int i = 0; i < 64; i++) wcol[i] = Win[i*256 + tid];
    for (int r = 0; r < 35; r++) {
      float acc = 0.f;
      #pragma unroll
      for (int i = 0; i < 64; i++) acc = fmaf(s_in[r*64 + i], wcol[i], acc);
      s_big[r*256 + tid] = acc;
    }
  }
  __syncthreads();
  for (int i = tid; i < 32*128; i += 256) {
    int tau = i >> 7, d = i & 127;
    float acc = bconv[d];
    #pragma unroll
    for (int k = 0; k < 4; k++) acc = fmaf(s_big[(tau + k)*256 + d], Wconv[d*4 + k], acc);
    float xiv = siluf(acc);
    s_xi[i] = xiv;
    int g = (b*TLEN + t0 + tau)*DI + d;
    xibuf[g] = xiv;
    float rv = s_big[(tau + 3)*256 + 128 + d];
    resgbuf[g] = siluf(rv);
  }
  __syncthreads();
  for (int i = tid; i < 128*68; i += 256) s_big[i] = Wxproj[i];
  __syncthreads();
  for (int i = tid; i < 32*68; i += 256) {
    int tau = i / 68, c = i % 68;
    float acc = 0.f;
    for (int k = 0; k < 128; k++) acc = fmaf(s_xi[tau*128 + k], s_big[k*68 + c], acc);
    if (c < 4)        s_dtr[tau*4 + c] = acc;
    else if (c < 36)  Bbuf[(b*TLEN + t0 + tau)*DS + (c - 4)]  = acc;
    else              Cbuf[(b*TLEN + t0 + tau)*DS + (c - 36)] = acc;
  }
  __syncthreads();
  for (int i = tid; i < 32*128; i += 256) {
    int tau = i >> 7, d = i & 127;
    float acc = bdt[d];
    #pragma unroll
    for (int r = 0; r < 4; r++) acc = fmaf(s_dtr[tau*4 + r], Wdt[r*128 + d], acc);
    float dtv = softplusf(acc);
    int g = (b*TLEN + t0 + tau)*DI + d;
    ddbuf[g] = make_float2(dtv, dtv * s_xi[i]);
  }
}

// ---------------- scan helpers: register staging of one 64-step tile ----------------
__device__ __forceinline__ void stage_load(const float2* __restrict__ ddg, const float* __restrict__ Bg,
    const float* __restrict__ Cg, int tid, float4& rdd, float4* rB, float4* rC)
{
  int t = tid >> 1, half = tid & 1;
  rdd = *(const float4*)((const float*)(ddg + (size_t)t*DI) + half*4);
  #pragma unroll
  for (int j = 0; j < 4; j++) {
    int q = tid + 128*j; int tt = q >> 3, k4 = q & 7;
    rB[j] = *(const float4*)(Bg + tt*DS + k4*4);
    rC[j] = *(const float4*)(Cg + tt*DS + k4*4);
  }
}

__device__ __forceinline__ void stage_write(float2 (*sdd)[64], float (*sBt)[68], float (*sCt)[68],
    int tid, float4 rdd, const float4* rB, const float4* rC)
{
  int t = tid >> 1, half = tid & 1;
  sdd[2*half+0][t] = make_float2(rdd.x, rdd.y);
  sdd[2*half+1][t] = make_float2(rdd.z, rdd.w);
  #pragma unroll
  for (int j = 0; j < 4; j++) {
    int q = tid + 128*j; int tt = q >> 3, k4 = q & 7;
    sBt[k4*4+0][tt] = rB[j].x; sBt[k4*4+1][tt] = rB[j].y;
    sBt[k4*4+2][tt] = rB[j].z; sBt[k4*4+3][tt] = rB[j].w;
    sCt[k4*4+0][tt] = rC[j].x; sCt[k4*4+1][tt] = rC[j].y;
    sCt[k4*4+2][tt] = rC[j].z; sCt[k4*4+3][tt] = rC[j].w;
  }
}

// ---------------- scan: h = exp(dt*A)*h + (dt*x)*B ; y = sum_s h*C ----------------
// 128 threads = 4 channels x 32 states; double-buffered reg-staged LDS tiles of 64 steps.
// Recurrence stores p = h*C to LDS (batched b128); y-pass sums over s with no shuffles.
__global__ __launch_bounds__(128) void scan_kernel(
    const float2* __restrict__ ddbuf, const float* __restrict__ Bbuf, const float* __restrict__ Cbuf,
    const float* __restrict__ Alog, float* __restrict__ ysbuf)
{
  __shared__ float2 s_dd[2][4][64];
  __shared__ float  s_Bt[2][32][68];
  __shared__ float  s_Ct[2][32][68];
  __shared__ float  s_p[128][68];
  const int tid = threadIdx.x;
  const int ch = tid >> 5, s = tid & 31;
  const int b  = blockIdx.x >> 5;
  const int d0 = (blockIdx.x & 31) * 4;
  const float A = -__expf(Alog[(d0 + ch)*DS + s]);
  const float2* ddg = ddbuf + (size_t)(b*TLEN)*DI + d0;
  const float*  Bg  = Bbuf + (size_t)(b*TLEN)*DS;
  const float*  Cg  = Cbuf + (size_t)(b*TLEN)*DS;

  float4 rdd, rB[4], rC[4];
  stage_load(ddg, Bg, Cg, tid, rdd, rB, rC);
  stage_write(s_dd[0], s_Bt[0], s_Ct[0], tid, rdd, rB, rC);
  __syncthreads();

  float h = 0.f;
  for (int kk = 0; kk < 16; kk++) {
    const int cur = kk & 1;
    const bool more = (kk < 15);
    if (more)
      stage_load(ddg + (size_t)(kk+1)*64*DI, Bg + (size_t)(kk+1)*64*DS, Cg + (size_t)(kk+1)*64*DS,
                 tid, rdd, rB, rC);
    // ---- recurrence over 64 steps, batched LDS access ----
    {
      const float4* dd4 = (const float4*)&s_dd[cur][ch][0];
      const float4* bt4 = (const float4*)&s_Bt[cur][s][0];
      const float4* ct4 = (const float4*)&s_Ct[cur][s][0];
      float4* pp4 = (float4*)&s_p[tid][0];
      #pragma unroll
      for (int j = 0; j < 8; j++) {
        float4 e0 = dd4[4*j+0], e1 = dd4[4*j+1], e2 = dd4[4*j+2], e3 = dd4[4*j+3];
        float4 bb0 = bt4[2*j], bb1 = bt4[2*j+1];
        float4 cc0 = ct4[2*j], cc1 = ct4[2*j+1];
        float p0,p1,p2,p3,p4,p5,p6,p7;
        h = fmaf(__expf(e0.x*A), h, e0.y*bb0.x); p0 = h*cc0.x;
        h = fmaf(__expf(e0.z*A), h, e0.w*bb0.y); p1 = h*cc0.y;
        h = fmaf(__expf(e1.x*A), h, e1.y*bb0.z); p2 = h*cc0.z;
        h = fmaf(__expf(e1.z*A), h, e1.w*bb0.w); p3 = h*cc0.w;
        h = fmaf(__expf(e2.x*A), h, e2.y*bb1.x); p4 = h*cc1.x;
        h = fmaf(__expf(e2.z*A), h, e2.w*bb1.y); p5 = h*cc1.y;
        h = fmaf(__expf(e3.x*A), h, e3.y*bb1.z); p6 = h*cc1.z;
        h = fmaf(__expf(e3.z*A), h, e3.w*bb1.w); p7 = h*cc1.w;
        pp4[2*j]   = make_float4(p0,p1,p2,p3);
        pp4[2*j+1] = make_float4(p4,p5,p6,p7);
      }
    }
    __syncthreads();
    // ---- y-pass: y[t,d] = sum_s p[s][t] ----
    {
      const int ch2 = tid & 3;
      const int t2  = (tid >> 2) << 1;
      float ax = 0.f, ay = 0.f;
      #pragma unroll
      for (int s2 = 0; s2 < 32; s2++) {
        float2 v = *(const float2*)&s_p[ch2*32 + s2][t2];
        ax += v.x; ay += v.y;
      }
      int g = (b*TLEN + kk*64 + t2)*DI + d0 + ch2;
      ysbuf[g]      = ax;
      ysbuf[g + DI] = ay;
    }
    if (more)
      stage_write(s_dd[cur^1], s_Bt[cur^1], s_Ct[cur^1], tid, rdd, rB, rC);
    __syncthreads();
  }
}

// ---------------- post: y = (ys + xi*Dp)*silu_gate; out = (window-base or +=) y @ Wout ----------------
__global__ __launch_bounds__(256) void post_kernel(
    const float* __restrict__ ysbuf, const float* __restrict__ xibuf, const float* __restrict__ resgbuf,
    const float* __restrict__ Dp, const float* __restrict__ Wout,
    const float* __restrict__ zsrc, const float* __restrict__ pzsrc, int shift,
    float* __restrict__ outbuf)
{
  __shared__ float s_y[32*128];
  __shared__ float s_w[128*64];
  const int tid = threadIdx.x;
  const int b  = blockIdx.x >> 5;
  const int t0 = (blockIdx.x & 31) * 32;
  for (int i = tid; i < 128*64; i += 256) s_w[i] = Wout[i];
  for (int i = tid; i < 32*128; i += 256) {
    int g = (b*TLEN + t0)*DI + i;
    s_y[i] = (ysbuf[g] + xibuf[g]*Dp[i & 127]) * resgbuf[g];
  }
  __syncthreads();
  for (int i = tid; i < 32*64; i += 256) {
    int tau = i >> 6, c = i & 63;
    float acc = 0.f;
    for (int dd = 0; dd < 128; dd++) acc = fmaf(s_y[tau*128 + dd], s_w[dd*64 + c], acc);
    int g = (b*TLEN + t0 + tau)*DM + c;
    float base;
    if (zsrc) {
      int st = t0 + tau + shift;
      base = (st < TLEN) ? zsrc[(b*TLEN + st)*DM + c] : pzsrc[(b*4 + (st - TLEN))*DM + c];
    } else {
      base = outbuf[g];
    }
    outbuf[g] = base + acc;
  }
}

// ---------------- layernorm over DM=64 per token ----------------
__global__ __launch_bounds__(256) void ln_kernel(
    const float* __restrict__ src, const float* __restrict__ g, const float* __restrict__ be,
    float* __restrict__ dst, float* __restrict__ predz, int slot, int full)
{
  int wid  = (blockIdx.x * blockDim.x + threadIdx.x) >> 6;
  int lane = threadIdx.x & 63;
  int token, b;
  if (full) { token = wid; if (token >= NTOK) return; b = token >> 10; }
  else      { b = wid; if (b >= BSZ) return; token = b*TLEN + (TLEN-1); }
  float v = src[token*DM + lane];
  float sum = v;
  #pragma unroll
  for (int m = 1; m < 64; m <<= 1) sum += __shfl_xor(sum, m);
  float mean = sum * (1.f/64.f);
  float dv = v - mean;
  float vs = dv*dv;
  #pragma unroll
  for (int m = 1; m < 64; m <<= 1) vs += __shfl_xor(vs, m);
  float var = vs * (1.f/64.f);
  float o = dv * rsqrtf(var + 1e-5f) * g[lane] + be[lane];
  if (dst) dst[token*DM + lane] = o;
  if (predz && ((token & (TLEN-1)) == TLEN-1)) predz[(b*4 + slot)*DM + lane] = o;
}

extern "C" void kernel_launch(void* const* d_in, const int* in_sizes, int n_in,
                              void* d_out, int out_size, void* d_ws, size_t ws_size,
                              hipStream_t stream)
{
  (void)in_sizes; (void)n_in; (void)out_size; (void)ws_size;
  const float* x     = (const float*)d_in[0];
  const float* We1   = (const float*)d_in[1];
  const float* be1   = (const float*)d_in[2];
  const float* We2   = (const float*)d_in[3];
  const float* be2   = (const float*)d_in[4];
  const float* Wd1   = (const float*)d_in[5];
  const float* bd1   = (const float*)d_in[6];
  const float* Wd2   = (const float*)d_in[7];
  const float* bd2   = (const float*)d_in[8];
  const float* Win   = (const float*)d_in[9];
  const float* Wconv = (const float*)d_in[10];
  const float* bconv = (const float*)d_in[11];
  const float* Wxp   = (const float*)d_in[12];
  const float* Wdt   = (const float*)d_in[13];
  const float* bdt   = (const float*)d_in[14];
  const float* Alog  = (const float*)d_in[15];
  const float* Dp    = (const float*)d_in[16];
  const float* Wout  = (const float*)d_in[17];
  const float* gamma = (const float*)d_in[18];
  const float* beta  = (const float*)d_in[19];

  float* o      = (float*)d_out;
  float* x_rec  = o;                 // 8*1024*32
  float* x_dyn  = o + 262144;        // 8*1024*32
  float* x_pred = o + 524288;        // 8*4*32
  float* z      = o + 525312;        // 8*1024*64
  float* zdyn   = o + 1049600;       // 8*1024*64

  float* w     = (float*)d_ws;
  float* cur   = w;                  // 524288
  float* xi    = cur  + 524288;      // 1048576
  float* resg  = xi   + 1048576;     // 1048576
  float2* dd   = (float2*)(resg + 1048576);  // 1048576 float2 = 2097152 floats
  float* Bb    = resg + 1048576 + 2097152;   // 262144
  float* Cb    = Bb   + 262144;      // 262144
  float* ys    = Cb   + 262144;      // 1048576
  float* predz = ys   + 1048576;     // 8*4*64

  // encoder: z = mlp(x);  x_rec = dec(z)
  mlp_kernel<32,64,64><<<dim3(NTOK/64), dim3(64), 0, stream>>>(x, We1, be1, We2, be2, z, NTOK);
  mlp_kernel<64,64,32><<<dim3(NTOK/64), dim3(64), 0, stream>>>(z, Wd1, bd1, Wd2, bd2, x_rec, NTOK);

  // 4 dynamics passes: pass 0 -> z_dyn (+ predz[0]); passes 1..3 -> predz[1..3]
  for (int p = 0; p < 4; p++) {
    for (int i = 0; i < 2; i++) {
      const float* Win_i   = Win   + (size_t)i*64*256;
      const float* Wconv_i = Wconv + (size_t)i*128*4;
      const float* bconv_i = bconv + (size_t)i*128;
      const float* Wxp_i   = Wxp   + (size_t)i*128*68;
      const float* Wdt_i   = Wdt   + (size_t)i*4*128;
      const float* bdt_i   = bdt   + (size_t)i*128;
      const float* Alog_i  = Alog  + (size_t)i*128*32;
      const float* Dp_i    = Dp    + (size_t)i*128;
      const float* Wout_i  = Wout  + (size_t)i*128*64;
      const float* zs = (i == 0) ? z : nullptr;   // block 0 reads windowed z/predz directly
      pre_kernel <<<dim3(256), dim3(256), 0, stream>>>(cur, zs, predz, p,
                                                       Win_i, Wconv_i, bconv_i, Wxp_i, Wdt_i, bdt_i,
                                                       xi, resg, dd, Bb, Cb);
      scan_kernel<<<dim3(256), dim3(128), 0, stream>>>(dd, Bb, Cb, Alog_i, ys);
      post_kernel<<<dim3(256), dim3(256), 0, stream>>>(ys, xi, resg, Dp_i, Wout_i,
                                                       zs, predz, p, cur);
    }
    if (p == 0)
      ln_kernel<<<dim3(NTOK/4), dim3(256), 0, stream>>>(cur, gamma, beta, zdyn, predz, 0, 1);
    else
      ln_kernel<<<dim3(2), dim3(256), 0, stream>>>(cur, gamma, beta, (float*)nullptr, predz, p, 0);
  }

  // x_dyn = dec(z_dyn); x_pred = dec(predz)
  mlp_kernel<64,64,32><<<dim3(NTOK/64), dim3(64), 0, stream>>>(zdyn, Wd1, bd1, Wd2, bd2, x_dyn, NTOK);
  mlp_kernel<64,64,32><<<dim3(1), dim3(64), 0, stream>>>(predz, Wd1, bd1, Wd2, bd2, x_pred, 32);
}

// Round 3
// 740.606 us; speedup vs baseline: 3.3635x; 1.2347x over previous
//
#include <hip/hip_runtime.h>

#define BSZ 8
#define TLEN 1024
#define DIN 32
#define DM 64
#define DI 128
#define DS 32
#define NTOK (BSZ*TLEN)

__device__ __forceinline__ float siluf(float x) { return x / (1.f + expf(-x)); }
__device__ __forceinline__ float softplusf(float x) { return (x > 20.f) ? x : log1pf(expf(x)); }

// ---------------- per-token MLP: relu(x@W1+b1)@W2+b2 ----------------
// Two-stage: hidden tile in LDS, then outputs. 16 tokens/block, 256 threads.
template<int IN, int H, int OUT, int TT>
__global__ __launch_bounds__(256) void mlp_kernel(
    const float* __restrict__ x, const float* __restrict__ W1, const float* __restrict__ b1,
    const float* __restrict__ W2, const float* __restrict__ b2, float* __restrict__ out)
{
  __shared__ float s_x[TT*IN];
  __shared__ float s_h[TT*H];
  const int tid = threadIdx.x;
  const int t0 = blockIdx.x * TT;
  for (int i = tid; i < TT*IN; i += 256) s_x[i] = x[t0*IN + i];
  __syncthreads();
  #pragma unroll
  for (int u = 0; u < (TT*H + 255)/256; u++) {
    int i = tid + u*256;
    if (i < TT*H) {
      int t = i / H, j = i % H;
      float acc = b1[j];
      for (int k = 0; k < IN; k++) acc = fmaf(s_x[t*IN + k], W1[k*H + j], acc);
      s_h[i] = fmaxf(acc, 0.f);
    }
  }
  __syncthreads();
  #pragma unroll
  for (int u = 0; u < (TT*OUT + 255)/256; u++) {
    int i = tid + u*256;
    if (i < TT*OUT) {
      int t = i / OUT, c = i % OUT;
      float acc = b2[c];
      for (int k = 0; k < H; k++) acc = fmaf(s_h[t*H + k], W2[k*OUT + c], acc);
      out[(t0 + t)*OUT + c] = acc;
    }
  }
}

// ---------------- pre: (windowed input) -> xz GEMM + causal conv + silu + xproj + dt ----------------
// 16 tokens/block (+3 halo), 512 blocks, 256 threads, ~33KB LDS.
__global__ __launch_bounds__(256) void pre_kernel(
    const float* __restrict__ inbuf, const float* __restrict__ zsrc, const float* __restrict__ pzsrc, int shift,
    const float* __restrict__ Win, const float* __restrict__ Wconv, const float* __restrict__ bconv,
    const float* __restrict__ Wxproj, const float* __restrict__ Wdt, const float* __restrict__ bdt,
    float* __restrict__ xibuf, float* __restrict__ resgbuf,
    float2* __restrict__ ddbuf, float* __restrict__ Bbuf, float* __restrict__ Cbuf)
{
  __shared__ float s_in[19*64];
  __shared__ float s_xz[19*256];
  __shared__ float s_xi[16*128];
  __shared__ float s_dtr[16*4];
  const int tid = threadIdx.x;
  const int b  = blockIdx.x >> 6;
  const int t0 = (blockIdx.x & 63) * 16;

  for (int i = tid; i < 19*64; i += 256) {
    int r = i >> 6, c = i & 63;
    int tg = t0 - 3 + r;
    float v = 0.f;
    if (tg >= 0) {
      if (zsrc) {
        int st = tg + shift;
        v = (st < TLEN) ? zsrc[(b*TLEN + st)*DM + c] : pzsrc[(b*4 + (st - TLEN))*DM + c];
      } else {
        v = inbuf[(b*TLEN + tg)*DM + c];
      }
    }
    s_in[i] = v;
  }
  __syncthreads();
  // xz = in @ Win : thread owns column tid; 19 register-row accumulators (19-way ILP)
  {
    float acc[19];
    #pragma unroll
    for (int r = 0; r < 19; r++) acc[r] = 0.f;
    for (int k = 0; k < 64; k++) {
      float wv = Win[k*256 + tid];
      #pragma unroll
      for (int r = 0; r < 19; r++) acc[r] = fmaf(s_in[r*64 + k], wv, acc[r]);
    }
    #pragma unroll
    for (int r = 0; r < 19; r++) s_xz[r*256 + tid] = acc[r];
  }
  __syncthreads();
  // causal conv (K=4) + bias + silu on xi half; silu gate on res half
  #pragma unroll
  for (int u = 0; u < 8; u++) {
    int i = tid + u*256;
    int tau = i >> 7, d = i & 127;
    float acc = bconv[d];
    #pragma unroll
    for (int k = 0; k < 4; k++) acc = fmaf(s_xz[(tau + k)*256 + d], Wconv[d*4 + k], acc);
    float xiv = siluf(acc);
    s_xi[i] = xiv;
    int g = (b*TLEN + t0 + tau)*DI + d;
    xibuf[g] = xiv;
    resgbuf[g] = siluf(s_xz[(tau + 3)*256 + 128 + d]);
  }
  __syncthreads();
  // xdbl = xi @ Wxproj : 16 tokens x 68 cols (weights from global, L1/L2-hot)
  #pragma unroll
  for (int u = 0; u < 5; u++) {
    int i = tid + u*256;
    if (i < 16*68) {
      int tau = i / 68, c = i % 68;
      float acc = 0.f;
      for (int k = 0; k < 128; k++) acc = fmaf(s_xi[tau*128 + k], Wxproj[k*68 + c], acc);
      if (c < 4)        s_dtr[tau*4 + c] = acc;
      else if (c < 36)  Bbuf[(b*TLEN + t0 + tau)*DS + (c - 4)]  = acc;
      else              Cbuf[(b*TLEN + t0 + tau)*DS + (c - 36)] = acc;
    }
  }
  __syncthreads();
  // dt = softplus(dtr @ Wdt + bdt); dd = (dt, dt*xi)
  #pragma unroll
  for (int u = 0; u < 8; u++) {
    int i = tid + u*256;
    int tau = i >> 7, d = i & 127;
    float acc = bdt[d];
    #pragma unroll
    for (int r = 0; r < 4; r++) acc = fmaf(s_dtr[tau*4 + r], Wdt[r*128 + d], acc);
    float dtv = softplusf(acc);
    int g = (b*TLEN + t0 + tau)*DI + d;
    ddbuf[g] = make_float2(dtv, dtv * s_xi[i]);
  }
}

// ---------------- scan helpers: register staging of one 64-step tile ----------------
__device__ __forceinline__ void stage_load(const float2* __restrict__ ddg, const float* __restrict__ Bg,
    const float* __restrict__ Cg, int tid, float4& rdd, float4* rB, float4* rC)
{
  int t = tid >> 1, half = tid & 1;
  rdd = *(const float4*)((const float*)(ddg + (size_t)t*DI) + half*4);
  #pragma unroll
  for (int j = 0; j < 4; j++) {
    int q = tid + 128*j; int tt = q >> 3, k4 = q & 7;
    rB[j] = *(const float4*)(Bg + tt*DS + k4*4);
    rC[j] = *(const float4*)(Cg + tt*DS + k4*4);
  }
}

__device__ __forceinline__ void stage_write(float2 (*sdd)[64], float (*sBt)[68], float (*sCt)[68],
    int tid, float4 rdd, const float4* rB, const float4* rC)
{
  int t = tid >> 1, half = tid & 1;
  sdd[2*half+0][t] = make_float2(rdd.x, rdd.y);
  sdd[2*half+1][t] = make_float2(rdd.z, rdd.w);
  #pragma unroll
  for (int j = 0; j < 4; j++) {
    int q = tid + 128*j; int tt = q >> 3, k4 = q & 7;
    sBt[k4*4+0][tt] = rB[j].x; sBt[k4*4+1][tt] = rB[j].y;
    sBt[k4*4+2][tt] = rB[j].z; sBt[k4*4+3][tt] = rB[j].w;
    sCt[k4*4+0][tt] = rC[j].x; sCt[k4*4+1][tt] = rC[j].y;
    sCt[k4*4+2][tt] = rC[j].z; sCt[k4*4+3][tt] = rC[j].w;
  }
}

// ---------------- scan: h = exp(dt*A)*h + (dt*x)*B ; y = sum_s h*C ----------------
__global__ __launch_bounds__(128) void scan_kernel(
    const float2* __restrict__ ddbuf, const float* __restrict__ Bbuf, const float* __restrict__ Cbuf,
    const float* __restrict__ Alog, float* __restrict__ ysbuf)
{
  __shared__ float2 s_dd[2][4][64];
  __shared__ float  s_Bt[2][32][68];
  __shared__ float  s_Ct[2][32][68];
  __shared__ float  s_p[128][68];
  const int tid = threadIdx.x;
  const int ch = tid >> 5, s = tid & 31;
  const int b  = blockIdx.x >> 5;
  const int d0 = (blockIdx.x & 31) * 4;
  const float A = -__expf(Alog[(d0 + ch)*DS + s]);
  const float2* ddg = ddbuf + (size_t)(b*TLEN)*DI + d0;
  const float*  Bg  = Bbuf + (size_t)(b*TLEN)*DS;
  const float*  Cg  = Cbuf + (size_t)(b*TLEN)*DS;

  float4 rdd, rB[4], rC[4];
  stage_load(ddg, Bg, Cg, tid, rdd, rB, rC);
  stage_write(s_dd[0], s_Bt[0], s_Ct[0], tid, rdd, rB, rC);
  __syncthreads();

  float h = 0.f;
  for (int kk = 0; kk < 16; kk++) {
    const int cur = kk & 1;
    const bool more = (kk < 15);
    if (more)
      stage_load(ddg + (size_t)(kk+1)*64*DI, Bg + (size_t)(kk+1)*64*DS, Cg + (size_t)(kk+1)*64*DS,
                 tid, rdd, rB, rC);
    {
      const float4* dd4 = (const float4*)&s_dd[cur][ch][0];
      const float4* bt4 = (const float4*)&s_Bt[cur][s][0];
      const float4* ct4 = (const float4*)&s_Ct[cur][s][0];
      float4* pp4 = (float4*)&s_p[tid][0];
      #pragma unroll
      for (int j = 0; j < 8; j++) {
        float4 e0 = dd4[4*j+0], e1 = dd4[4*j+1], e2 = dd4[4*j+2], e3 = dd4[4*j+3];
        float4 bb0 = bt4[2*j], bb1 = bt4[2*j+1];
        float4 cc0 = ct4[2*j], cc1 = ct4[2*j+1];
        float p0,p1,p2,p3,p4,p5,p6,p7;
        h = fmaf(__expf(e0.x*A), h, e0.y*bb0.x); p0 = h*cc0.x;
        h = fmaf(__expf(e0.z*A), h, e0.w*bb0.y); p1 = h*cc0.y;
        h = fmaf(__expf(e1.x*A), h, e1.y*bb0.z); p2 = h*cc0.z;
        h = fmaf(__expf(e1.z*A), h, e1.w*bb0.w); p3 = h*cc0.w;
        h = fmaf(__expf(e2.x*A), h, e2.y*bb1.x); p4 = h*cc1.x;
        h = fmaf(__expf(e2.z*A), h, e2.w*bb1.y); p5 = h*cc1.y;
        h = fmaf(__expf(e3.x*A), h, e3.y*bb1.z); p6 = h*cc1.z;
        h = fmaf(__expf(e3.z*A), h, e3.w*bb1.w); p7 = h*cc1.w;
        pp4[2*j]   = make_float4(p0,p1,p2,p3);
        pp4[2*j+1] = make_float4(p4,p5,p6,p7);
      }
    }
    __syncthreads();
    {
      const int ch2 = tid & 3;
      const int t2  = (tid >> 2) << 1;
      float ax = 0.f, ay = 0.f;
      #pragma unroll
      for (int s2 = 0; s2 < 32; s2++) {
        float2 v = *(const float2*)&s_p[ch2*32 + s2][t2];
        ax += v.x; ay += v.y;
      }
      int g = (b*TLEN + kk*64 + t2)*DI + d0 + ch2;
      ysbuf[g]      = ax;
      ysbuf[g + DI] = ay;
    }
    if (more)
      stage_write(s_dd[cur^1], s_Bt[cur^1], s_Ct[cur^1], tid, rdd, rB, rC);
    __syncthreads();
  }
}

// ---------------- post: y = (ys + xi*Dp)*silu_gate; out = (window-base or +=) y @ Wout ----------------
// 16 tokens/block, 512 blocks.
__global__ __launch_bounds__(256) void post_kernel(
    const float* __restrict__ ysbuf, const float* __restrict__ xibuf, const float* __restrict__ resgbuf,
    const float* __restrict__ Dp, const float* __restrict__ Wout,
    const float* __restrict__ zsrc, const float* __restrict__ pzsrc, int shift,
    float* __restrict__ outbuf)
{
  __shared__ float s_y[16*128];
  const int tid = threadIdx.x;
  const int b  = blockIdx.x >> 6;
  const int t0 = (blockIdx.x & 63) * 16;
  #pragma unroll
  for (int u = 0; u < 8; u++) {
    int i = tid + u*256;
    int g = (b*TLEN + t0)*DI + i;
    s_y[i] = (ysbuf[g] + xibuf[g]*Dp[i & 127]) * resgbuf[g];
  }
  __syncthreads();
  #pragma unroll
  for (int u = 0; u < 4; u++) {
    int i = tid + u*256;
    int tau = i >> 6, c = i & 63;
    float acc = 0.f;
    for (int dd = 0; dd < 128; dd++) acc = fmaf(s_y[tau*128 + dd], Wout[dd*64 + c], acc);
    int g = (b*TLEN + t0 + tau)*DM + c;
    float base;
    if (zsrc) {
      int st = t0 + tau + shift;
      base = (st < TLEN) ? zsrc[(b*TLEN + st)*DM + c] : pzsrc[(b*4 + (st - TLEN))*DM + c];
    } else {
      base = outbuf[g];
    }
    outbuf[g] = base + acc;
  }
}

// ---------------- layernorm over DM=64 per token ----------------
__global__ __launch_bounds__(256) void ln_kernel(
    const float* __restrict__ src, const float* __restrict__ g, const float* __restrict__ be,
    float* __restrict__ dst, float* __restrict__ predz, int slot, int full)
{
  int wid  = (blockIdx.x * blockDim.x + threadIdx.x) >> 6;
  int lane = threadIdx.x & 63;
  int token, b;
  if (full) { token = wid; if (token >= NTOK) return; b = token >> 10; }
  else      { b = wid; if (b >= BSZ) return; token = b*TLEN + (TLEN-1); }
  float v = src[token*DM + lane];
  float sum = v;
  #pragma unroll
  for (int m = 1; m < 64; m <<= 1) sum += __shfl_xor(sum, m);
  float mean = sum * (1.f/64.f);
  float dv = v - mean;
  float vs = dv*dv;
  #pragma unroll
  for (int m = 1; m < 64; m <<= 1) vs += __shfl_xor(vs, m);
  float var = vs * (1.f/64.f);
  float o = dv * rsqrtf(var + 1e-5f) * g[lane] + be[lane];
  if (dst) dst[token*DM + lane] = o;
  if (predz && ((token & (TLEN-1)) == TLEN-1)) predz[(b*4 + slot)*DM + lane] = o;
}

extern "C" void kernel_launch(void* const* d_in, const int* in_sizes, int n_in,
                              void* d_out, int out_size, void* d_ws, size_t ws_size,
                              hipStream_t stream)
{
  (void)in_sizes; (void)n_in; (void)out_size; (void)ws_size;
  const float* x     = (const float*)d_in[0];
  const float* We1   = (const float*)d_in[1];
  const float* be1   = (const float*)d_in[2];
  const float* We2   = (const float*)d_in[3];
  const float* be2   = (const float*)d_in[4];
  const float* Wd1   = (const float*)d_in[5];
  const float* bd1   = (const float*)d_in[6];
  const float* Wd2   = (const float*)d_in[7];
  const float* bd2   = (const float*)d_in[8];
  const float* Win   = (const float*)d_in[9];
  const float* Wconv = (const float*)d_in[10];
  const float* bconv = (const float*)d_in[11];
  const float* Wxp   = (const float*)d_in[12];
  const float* Wdt   = (const float*)d_in[13];
  const float* bdt   = (const float*)d_in[14];
  const float* Alog  = (const float*)d_in[15];
  const float* Dp    = (const float*)d_in[16];
  const float* Wout  = (const float*)d_in[17];
  const float* gamma = (const float*)d_in[18];
  const float* beta  = (const float*)d_in[19];

  float* o      = (float*)d_out;
  float* x_rec  = o;                 // 8*1024*32
  float* x_dyn  = o + 262144;        // 8*1024*32
  float* x_pred = o + 524288;        // 8*4*32
  float* z      = o + 525312;        // 8*1024*64
  float* zdyn   = o + 1049600;       // 8*1024*64

  float* w     = (float*)d_ws;
  float* cur   = w;                  // 524288
  float* xi    = cur  + 524288;      // 1048576
  float* resg  = xi   + 1048576;     // 1048576
  float2* dd   = (float2*)(resg + 1048576);  // 1048576 float2
  float* Bb    = resg + 1048576 + 2097152;   // 262144
  float* Cb    = Bb   + 262144;      // 262144
  float* ys    = Cb   + 262144;      // 1048576
  float* predz = ys   + 1048576;     // 8*4*64

  // encoder: z = mlp(x);  x_rec = dec(z)
  mlp_kernel<32,64,64,16><<<dim3(NTOK/16), dim3(256), 0, stream>>>(x, We1, be1, We2, be2, z);
  mlp_kernel<64,64,32,16><<<dim3(NTOK/16), dim3(256), 0, stream>>>(z, Wd1, bd1, Wd2, bd2, x_rec);

  // 4 dynamics passes: pass 0 -> z_dyn (+ predz[0]); passes 1..3 -> predz[1..3]
  for (int p = 0; p < 4; p++) {
    for (int i = 0; i < 2; i++) {
      const float* Win_i   = Win   + (size_t)i*64*256;
      const float* Wconv_i = Wconv + (size_t)i*128*4;
      const float* bconv_i = bconv + (size_t)i*128;
      const float* Wxp_i   = Wxp   + (size_t)i*128*68;
      const float* Wdt_i   = Wdt   + (size_t)i*4*128;
      const float* bdt_i   = bdt   + (size_t)i*128;
      const float* Alog_i  = Alog  + (size_t)i*128*32;
      const float* Dp_i    = Dp    + (size_t)i*128;
      const float* Wout_i  = Wout  + (size_t)i*128*64;
      const float* zs = (i == 0) ? z : nullptr;   // block 0 reads windowed z/predz directly
      pre_kernel <<<dim3(512), dim3(256), 0, stream>>>(cur, zs, predz, p,
                                                       Win_i, Wconv_i, bconv_i, Wxp_i, Wdt_i, bdt_i,
                                                       xi, resg, dd, Bb, Cb);
      scan_kernel<<<dim3(256), dim3(128), 0, stream>>>(dd, Bb, Cb, Alog_i, ys);
      post_kernel<<<dim3(512), dim3(256), 0, stream>>>(ys, xi, resg, Dp_i, Wout_i,
                                                       zs, predz, p, cur);
    }
    if (p == 0)
      ln_kernel<<<dim3(NTOK/4), dim3(256), 0, stream>>>(cur, gamma, beta, zdyn, predz, 0, 1);
    else
      ln_kernel<<<dim3(2), dim3(256), 0, stream>>>(cur, gamma, beta, (float*)nullptr, predz, p, 0);
  }

  // x_dyn = dec(z_dyn); x_pred = dec(predz)
  mlp_kernel<64,64,32,16><<<dim3(NTOK/16), dim3(256), 0, stream>>>(zdyn, Wd1, bd1, Wd2, bd2, x_dyn);
  mlp_kernel<64,64,32,16><<<dim3(2), dim3(256), 0, stream>>>(predz, Wd1, bd1, Wd2, bd2, x_pred);
}

// Round 4
// 723.658 us; speedup vs baseline: 3.4423x; 1.0234x over previous
//
#include <hip/hip_runtime.h>

#define BSZ 8
#define TLEN 1024
#define DIN 32
#define DM 64
#define DI 128
#define DS 32
#define NTOK (BSZ*TLEN)
#define NCHUNK 16
#define CLEN 64

__device__ __forceinline__ float siluf(float x) { return x / (1.f + expf(-x)); }
__device__ __forceinline__ float softplusf(float x) { return (x > 20.f) ? x : log1pf(expf(x)); }

// ---------------- per-token MLP: relu(x@W1+b1)@W2+b2 ----------------
template<int IN, int H, int OUT, int TT>
__global__ __launch_bounds__(256) void mlp_kernel(
    const float* __restrict__ x, const float* __restrict__ W1, const float* __restrict__ b1,
    const float* __restrict__ W2, const float* __restrict__ b2, float* __restrict__ out)
{
  __shared__ float s_x[TT*IN];
  __shared__ float s_h[TT*H];
  const int tid = threadIdx.x;
  const int t0 = blockIdx.x * TT;
  for (int i = tid; i < TT*IN; i += 256) s_x[i] = x[t0*IN + i];
  __syncthreads();
  #pragma unroll
  for (int u = 0; u < (TT*H + 255)/256; u++) {
    int i = tid + u*256;
    if (i < TT*H) {
      int t = i / H, j = i % H;
      float acc = b1[j];
      for (int k = 0; k < IN; k++) acc = fmaf(s_x[t*IN + k], W1[k*H + j], acc);
      s_h[i] = fmaxf(acc, 0.f);
    }
  }
  __syncthreads();
  #pragma unroll
  for (int u = 0; u < (TT*OUT + 255)/256; u++) {
    int i = tid + u*256;
    if (i < TT*OUT) {
      int t = i / OUT, c = i % OUT;
      float acc = b2[c];
      for (int k = 0; k < H; k++) acc = fmaf(s_h[t*H + k], W2[k*OUT + c], acc);
      out[(t0 + t)*OUT + c] = acc;
    }
  }
}

// ---------------- pre: window -> xz GEMM -> conv/silu in registers -> xproj -> dt ----------------
// 16 tokens/block, 512 blocks, 256 threads, ~13KB LDS.
__global__ __launch_bounds__(256) void pre_kernel(
    const float* __restrict__ inbuf, const float* __restrict__ zsrc, const float* __restrict__ pzsrc, int shift,
    const float* __restrict__ Win, const float* __restrict__ Wconv, const float* __restrict__ bconv,
    const float* __restrict__ Wxproj, const float* __restrict__ Wdt, const float* __restrict__ bdt,
    float* __restrict__ xibuf, float* __restrict__ resgbuf,
    float2* __restrict__ ddbuf, float* __restrict__ Bbuf, float* __restrict__ Cbuf)
{
  __shared__ float s_in[19*64];
  __shared__ float s_xi[16*128];
  __shared__ float s_dtr[16*4];
  const int tid = threadIdx.x;
  const int b  = blockIdx.x >> 6;
  const int t0 = (blockIdx.x & 63) * 16;

  for (int i = tid; i < 19*64; i += 256) {
    int r = i >> 6, c = i & 63;
    int tg = t0 - 3 + r;
    float v = 0.f;
    if (tg >= 0) {
      if (zsrc) {
        int st = tg + shift;
        v = (st < TLEN) ? zsrc[(b*TLEN + st)*DM + c] : pzsrc[(b*4 + (st - TLEN))*DM + c];
      } else {
        v = inbuf[(b*TLEN + tg)*DM + c];
      }
    }
    s_in[i] = v;
  }
  __syncthreads();
  // xz GEMM: thread owns output column tid; rows (tokens t0-3..t0+15) in registers.
  float acc[19];
  #pragma unroll
  for (int r = 0; r < 19; r++) acc[r] = 0.f;
  #pragma unroll 2
  for (int k4 = 0; k4 < 16; k4++) {
    float w0 = Win[(k4*4+0)*256 + tid];
    float w1 = Win[(k4*4+1)*256 + tid];
    float w2 = Win[(k4*4+2)*256 + tid];
    float w3 = Win[(k4*4+3)*256 + tid];
    #pragma unroll
    for (int r = 0; r < 19; r++) {
      float4 xv = *(const float4*)&s_in[r*64 + k4*4];
      acc[r] = fmaf(xv.x, w0, acc[r]);
      acc[r] = fmaf(xv.y, w1, acc[r]);
      acc[r] = fmaf(xv.z, w2, acc[r]);
      acc[r] = fmaf(xv.w, w3, acc[r]);
    }
  }
  // conv (K=4) + silu entirely in registers (thread owns channel = column)
  if (tid < 128) {
    float4 wc = *(const float4*)&Wconv[tid*4];
    float bc = bconv[tid];
    #pragma unroll
    for (int tau = 0; tau < 16; tau++) {
      float v = bc;
      v = fmaf(acc[tau+0], wc.x, v);
      v = fmaf(acc[tau+1], wc.y, v);
      v = fmaf(acc[tau+2], wc.z, v);
      v = fmaf(acc[tau+3], wc.w, v);
      float xiv = siluf(v);
      s_xi[tau*128 + tid] = xiv;
      xibuf[(b*TLEN + t0 + tau)*DI + tid] = xiv;
    }
  } else {
    int d = tid - 128;
    #pragma unroll
    for (int tau = 0; tau < 16; tau++)
      resgbuf[(b*TLEN + t0 + tau)*DI + d] = siluf(acc[tau+3]);
  }
  __syncthreads();
  // xproj B/C cols: wave wv handles tokens wv*4..wv*4+3; lane c -> proj col 4+c
  {
    const int wv = tid >> 6, c = tid & 63;
    float a0 = 0.f, a1 = 0.f, a2 = 0.f, a3 = 0.f;
    const float4* x0 = (const float4*)&s_xi[(wv*4+0)*128];
    const float4* x1 = (const float4*)&s_xi[(wv*4+1)*128];
    const float4* x2 = (const float4*)&s_xi[(wv*4+2)*128];
    const float4* x3 = (const float4*)&s_xi[(wv*4+3)*128];
    #pragma unroll 2
    for (int k4 = 0; k4 < 32; k4++) {
      float wq0 = Wxproj[(k4*4+0)*68 + 4 + c];
      float wq1 = Wxproj[(k4*4+1)*68 + 4 + c];
      float wq2 = Wxproj[(k4*4+2)*68 + 4 + c];
      float wq3 = Wxproj[(k4*4+3)*68 + 4 + c];
      float4 v0 = x0[k4], v1 = x1[k4], v2 = x2[k4], v3 = x3[k4];
      a0 = fmaf(v0.x,wq0, fmaf(v0.y,wq1, fmaf(v0.z,wq2, fmaf(v0.w,wq3, a0))));
      a1 = fmaf(v1.x,wq0, fmaf(v1.y,wq1, fmaf(v1.z,wq2, fmaf(v1.w,wq3, a1))));
      a2 = fmaf(v2.x,wq0, fmaf(v2.y,wq1, fmaf(v2.z,wq2, fmaf(v2.w,wq3, a2))));
      a3 = fmaf(v3.x,wq0, fmaf(v3.y,wq1, fmaf(v3.z,wq2, fmaf(v3.w,wq3, a3))));
    }
    int tb = b*TLEN + t0 + wv*4;
    if (c < 32) {
      Bbuf[(tb+0)*DS + c] = a0; Bbuf[(tb+1)*DS + c] = a1;
      Bbuf[(tb+2)*DS + c] = a2; Bbuf[(tb+3)*DS + c] = a3;
    } else {
      int cc = c - 32;
      Cbuf[(tb+0)*DS + cc] = a0; Cbuf[(tb+1)*DS + cc] = a1;
      Cbuf[(tb+2)*DS + cc] = a2; Cbuf[(tb+3)*DS + cc] = a3;
    }
  }
  // dtr cols (4 per token), threads 0..63
  if (tid < 64) {
    int tau = tid >> 2, cc = tid & 3;
    float a = 0.f;
    const float4* xx = (const float4*)&s_xi[tau*128];
    #pragma unroll 4
    for (int k4 = 0; k4 < 32; k4++) {
      float4 v = xx[k4];
      a = fmaf(v.x, Wxproj[(k4*4+0)*68 + cc], a);
      a = fmaf(v.y, Wxproj[(k4*4+1)*68 + cc], a);
      a = fmaf(v.z, Wxproj[(k4*4+2)*68 + cc], a);
      a = fmaf(v.w, Wxproj[(k4*4+3)*68 + cc], a);
    }
    s_dtr[tau*4 + cc] = a;
  }
  __syncthreads();
  // dt = softplus(dtr @ Wdt + bdt); dd = (dt, dt*xi)
  #pragma unroll
  for (int u = 0; u < 8; u++) {
    int i = tid + u*256;
    int tau = i >> 7, d = i & 127;
    float a = bdt[d];
    #pragma unroll
    for (int r = 0; r < 4; r++) a = fmaf(s_dtr[tau*4 + r], Wdt[r*128 + d], a);
    float dtv = softplusf(a);
    ddbuf[(b*TLEN + t0 + tau)*DI + d] = make_float2(dtv, dtv * s_xi[i]);
  }
}

// ---------------- scan phase 1: per-chunk local scan from h=0 ----------------
// block = (b, chunk, dgroup); 128 thr = 4ch x 32s. Emits h_end and chunk decay exp(A*sum dt).
__global__ __launch_bounds__(128) void scan1_kernel(
    const float2* __restrict__ ddbuf, const float* __restrict__ Bbuf,
    const float* __restrict__ Alog, float* __restrict__ hend, float* __restrict__ hdec)
{
  __shared__ float2 s_dd[4][CLEN];
  __shared__ float  s_Bt[32][68];
  const int tid = threadIdx.x;
  const int ch = tid >> 5, s = tid & 31;
  const int dg = blockIdx.x & 31;
  const int c  = (blockIdx.x >> 5) & 15;
  const int b  = blockIdx.x >> 9;
  const int d0 = dg * 4;
  const float A = -__expf(Alog[(d0 + ch)*DS + s]);
  const float2* ddg = ddbuf + (size_t)(b*TLEN + c*CLEN)*DI + d0;
  const float*  Bg  = Bbuf  + (size_t)(b*TLEN + c*CLEN)*DS;
  {
    int t = tid >> 1, half = tid & 1;
    float4 rdd = *(const float4*)((const float*)(ddg + (size_t)t*DI) + half*4);
    s_dd[2*half+0][t] = make_float2(rdd.x, rdd.y);
    s_dd[2*half+1][t] = make_float2(rdd.z, rdd.w);
    #pragma unroll
    for (int j = 0; j < 4; j++) {
      int q = tid + 128*j; int tt = q >> 3, k4 = q & 7;
      float4 rB = *(const float4*)(Bg + tt*DS + k4*4);
      s_Bt[k4*4+0][tt] = rB.x; s_Bt[k4*4+1][tt] = rB.y;
      s_Bt[k4*4+2][tt] = rB.z; s_Bt[k4*4+3][tt] = rB.w;
    }
  }
  __syncthreads();
  float h = 0.f, dts = 0.f;
  const float4* dd4 = (const float4*)&s_dd[ch][0];
  const float4* bt4 = (const float4*)&s_Bt[s][0];
  #pragma unroll
  for (int j = 0; j < 8; j++) {
    float4 e0 = dd4[4*j+0], e1 = dd4[4*j+1], e2 = dd4[4*j+2], e3 = dd4[4*j+3];
    float4 bb0 = bt4[2*j], bb1 = bt4[2*j+1];
    h = fmaf(__expf(e0.x*A), h, e0.y*bb0.x);
    h = fmaf(__expf(e0.z*A), h, e0.w*bb0.y);
    h = fmaf(__expf(e1.x*A), h, e1.y*bb0.z);
    h = fmaf(__expf(e1.z*A), h, e1.w*bb0.w);
    h = fmaf(__expf(e2.x*A), h, e2.y*bb1.x);
    h = fmaf(__expf(e2.z*A), h, e2.w*bb1.y);
    h = fmaf(__expf(e3.x*A), h, e3.y*bb1.z);
    h = fmaf(__expf(e3.z*A), h, e3.w*bb1.w);
    dts += (e0.x + e0.z) + (e1.x + e1.z) + (e2.x + e2.z) + (e3.x + e3.z);
  }
  int o = ((b*NCHUNK + c)*DI + d0 + ch)*DS + s;
  hend[o] = h;
  hdec[o] = __expf(A*dts);
}

// ---------------- scan phase 2: combine 16 chunks -> per-chunk initial h0 ----------------
__global__ __launch_bounds__(256) void scan2_kernel(
    const float* __restrict__ hend, const float* __restrict__ hdec, float* __restrict__ h0buf)
{
  int idx = blockIdx.x*256 + threadIdx.x;  // (b, d, s)
  int b = idx >> 12, rem = idx & 4095;
  float h = 0.f;
  #pragma unroll
  for (int c = 0; c < NCHUNK; c++) {
    int o = (b*NCHUNK + c)*4096 + rem;
    h0buf[o] = h;
    h = fmaf(hdec[o], h, hend[o]);
  }
}

// ---------------- scan phase 3: rescan chunk from h0, emit y ----------------
__global__ __launch_bounds__(128) void scan3_kernel(
    const float2* __restrict__ ddbuf, const float* __restrict__ Bbuf, const float* __restrict__ Cbuf,
    const float* __restrict__ Alog, const float* __restrict__ h0buf, float* __restrict__ ysbuf)
{
  __shared__ float2 s_dd[4][CLEN];
  __shared__ float  s_Bt[32][68];
  __shared__ float  s_Ct[32][68];
  __shared__ float  s_p[128][68];
  const int tid = threadIdx.x;
  const int ch = tid >> 5, s = tid & 31;
  const int dg = blockIdx.x & 31;
  const int c  = (blockIdx.x >> 5) & 15;
  const int b  = blockIdx.x >> 9;
  const int d0 = dg * 4;
  const float A = -__expf(Alog[(d0 + ch)*DS + s]);
  const float2* ddg = ddbuf + (size_t)(b*TLEN + c*CLEN)*DI + d0;
  const float*  Bg  = Bbuf  + (size_t)(b*TLEN + c*CLEN)*DS;
  const float*  Cg  = Cbuf  + (size_t)(b*TLEN + c*CLEN)*DS;
  {
    int t = tid >> 1, half = tid & 1;
    float4 rdd = *(const float4*)((const float*)(ddg + (size_t)t*DI) + half*4);
    s_dd[2*half+0][t] = make_float2(rdd.x, rdd.y);
    s_dd[2*half+1][t] = make_float2(rdd.z, rdd.w);
    #pragma unroll
    for (int j = 0; j < 4; j++) {
      int q = tid + 128*j; int tt = q >> 3, k4 = q & 7;
      float4 rB = *(const float4*)(Bg + tt*DS + k4*4);
      float4 rC = *(const float4*)(Cg + tt*DS + k4*4);
      s_Bt[k4*4+0][tt] = rB.x; s_Bt[k4*4+1][tt] = rB.y;
      s_Bt[k4*4+2][tt] = rB.z; s_Bt[k4*4+3][tt] = rB.w;
      s_Ct[k4*4+0][tt] = rC.x; s_Ct[k4*4+1][tt] = rC.y;
      s_Ct[k4*4+2][tt] = rC.z; s_Ct[k4*4+3][tt] = rC.w;
    }
  }
  __syncthreads();
  float h = h0buf[((b*NCHUNK + c)*DI + d0 + ch)*DS + s];
  {
    const float4* dd4 = (const float4*)&s_dd[ch][0];
    const float4* bt4 = (const float4*)&s_Bt[s][0];
    const float4* ct4 = (const float4*)&s_Ct[s][0];
    float4* pp4 = (float4*)&s_p[tid][0];
    #pragma unroll
    for (int j = 0; j < 8; j++) {
      float4 e0 = dd4[4*j+0], e1 = dd4[4*j+1], e2 = dd4[4*j+2], e3 = dd4[4*j+3];
      float4 bb0 = bt4[2*j], bb1 = bt4[2*j+1];
      float4 cc0 = ct4[2*j], cc1 = ct4[2*j+1];
      float p0,p1,p2,p3,p4,p5,p6,p7;
      h = fmaf(__expf(e0.x*A), h, e0.y*bb0.x); p0 = h*cc0.x;
      h = fmaf(__expf(e0.z*A), h, e0.w*bb0.y); p1 = h*cc0.y;
      h = fmaf(__expf(e1.x*A), h, e1.y*bb0.z); p2 = h*cc0.z;
      h = fmaf(__expf(e1.z*A), h, e1.w*bb0.w); p3 = h*cc0.w;
      h = fmaf(__expf(e2.x*A), h, e2.y*bb1.x); p4 = h*cc1.x;
      h = fmaf(__expf(e2.z*A), h, e2.w*bb1.y); p5 = h*cc1.y;
      h = fmaf(__expf(e3.x*A), h, e3.y*bb1.z); p6 = h*cc1.z;
      h = fmaf(__expf(e3.z*A), h, e3.w*bb1.w); p7 = h*cc1.w;
      pp4[2*j]   = make_float4(p0,p1,p2,p3);
      pp4[2*j+1] = make_float4(p4,p5,p6,p7);
    }
  }
  __syncthreads();
  {
    const int ch2 = tid & 3;
    const int t2  = (tid >> 2) << 1;
    float ax = 0.f, ay = 0.f;
    #pragma unroll
    for (int s2 = 0; s2 < 32; s2++) {
      float2 v = *(const float2*)&s_p[ch2*32 + s2][t2];
      ax += v.x; ay += v.y;
    }
    int g = (b*TLEN + c*CLEN + t2)*DI + d0 + ch2;
    ysbuf[g]      = ax;
    ysbuf[g + DI] = ay;
  }
}

// ---------------- post: y = (ys + xi*Dp)*silu_gate; out = (window-base or +=) y @ Wout ----------------
__global__ __launch_bounds__(256) void post_kernel(
    const float* __restrict__ ysbuf, const float* __restrict__ xibuf, const float* __restrict__ resgbuf,
    const float* __restrict__ Dp, const float* __restrict__ Wout,
    const float* __restrict__ zsrc, const float* __restrict__ pzsrc, int shift,
    float* __restrict__ outbuf)
{
  __shared__ float s_y[16*128];
  const int tid = threadIdx.x;
  const int b  = blockIdx.x >> 6;
  const int t0 = (blockIdx.x & 63) * 16;
  #pragma unroll
  for (int u = 0; u < 8; u++) {
    int i = tid + u*256;
    int g = (b*TLEN + t0)*DI + i;
    s_y[i] = (ysbuf[g] + xibuf[g]*Dp[i & 127]) * resgbuf[g];
  }
  __syncthreads();
  #pragma unroll
  for (int u = 0; u < 4; u++) {
    int i = tid + u*256;
    int tau = i >> 6, c = i & 63;
    float a = 0.f;
    const float4* yy = (const float4*)&s_y[tau*128];
    #pragma unroll 4
    for (int k4 = 0; k4 < 32; k4++) {
      float4 v = yy[k4];
      a = fmaf(v.x, Wout[(k4*4+0)*64 + c], a);
      a = fmaf(v.y, Wout[(k4*4+1)*64 + c], a);
      a = fmaf(v.z, Wout[(k4*4+2)*64 + c], a);
      a = fmaf(v.w, Wout[(k4*4+3)*64 + c], a);
    }
    int g = (b*TLEN + t0 + tau)*DM + c;
    float base;
    if (zsrc) {
      int st = t0 + tau + shift;
      base = (st < TLEN) ? zsrc[(b*TLEN + st)*DM + c] : pzsrc[(b*4 + (st - TLEN))*DM + c];
    } else {
      base = outbuf[g];
    }
    outbuf[g] = base + a;
  }
}

// ---------------- layernorm over DM=64 per token ----------------
__global__ __launch_bounds__(256) void ln_kernel(
    const float* __restrict__ src, const float* __restrict__ g, const float* __restrict__ be,
    float* __restrict__ dst, float* __restrict__ predz, int slot, int full)
{
  int wid  = (blockIdx.x * blockDim.x + threadIdx.x) >> 6;
  int lane = threadIdx.x & 63;
  int token, b;
  if (full) { token = wid; if (token >= NTOK) return; b = token >> 10; }
  else      { b = wid; if (b >= BSZ) return; token = b*TLEN + (TLEN-1); }
  float v = src[token*DM + lane];
  float sum = v;
  #pragma unroll
  for (int m = 1; m < 64; m <<= 1) sum += __shfl_xor(sum, m);
  float mean = sum * (1.f/64.f);
  float dv = v - mean;
  float vs = dv*dv;
  #pragma unroll
  for (int m = 1; m < 64; m <<= 1) vs += __shfl_xor(vs, m);
  float var = vs * (1.f/64.f);
  float o = dv * rsqrtf(var + 1e-5f) * g[lane] + be[lane];
  if (dst) dst[token*DM + lane] = o;
  if (predz && ((token & (TLEN-1)) == TLEN-1)) predz[(b*4 + slot)*DM + lane] = o;
}

extern "C" void kernel_launch(void* const* d_in, const int* in_sizes, int n_in,
                              void* d_out, int out_size, void* d_ws, size_t ws_size,
                              hipStream_t stream)
{
  (void)in_sizes; (void)n_in; (void)out_size; (void)ws_size;
  const float* x     = (const float*)d_in[0];
  const float* We1   = (const float*)d_in[1];
  const float* be1   = (const float*)d_in[2];
  const float* We2   = (const float*)d_in[3];
  const float* be2   = (const float*)d_in[4];
  const float* Wd1   = (const float*)d_in[5];
  const float* bd1   = (const float*)d_in[6];
  const float* Wd2   = (const float*)d_in[7];
  const float* bd2   = (const float*)d_in[8];
  const float* Win   = (const float*)d_in[9];
  const float* Wconv = (const float*)d_in[10];
  const float* bconv = (const float*)d_in[11];
  const float* Wxp   = (const float*)d_in[12];
  const float* Wdt   = (const float*)d_in[13];
  const float* bdt   = (const float*)d_in[14];
  const float* Alog  = (const float*)d_in[15];
  const float* Dp    = (const float*)d_in[16];
  const float* Wout  = (const float*)d_in[17];
  const float* gamma = (const float*)d_in[18];
  const float* beta  = (const float*)d_in[19];

  float* o      = (float*)d_out;
  float* x_rec  = o;                 // 8*1024*32
  float* x_dyn  = o + 262144;        // 8*1024*32
  float* x_pred = o + 524288;        // 8*4*32
  float* z      = o + 525312;        // 8*1024*64
  float* zdyn   = o + 1049600;       // 8*1024*64

  float* w     = (float*)d_ws;
  float* cur   = w;                  // 524288
  float* xi    = cur  + 524288;      // 1048576
  float* resg  = xi   + 1048576;     // 1048576
  float2* dd   = (float2*)(resg + 1048576);  // 1048576 float2
  float* Bb    = resg + 1048576 + 2097152;   // 262144
  float* Cb    = Bb   + 262144;      // 262144
  float* ys    = Cb   + 262144;      // 1048576
  float* predz = ys   + 1048576;     // 2048
  float* hend  = predz + 2048;       // 524288
  float* hdec  = hend + 524288;      // 524288
  float* h0    = hdec + 524288;      // 524288

  // encoder: z = mlp(x);  x_rec = dec(z)
  mlp_kernel<32,64,64,16><<<dim3(NTOK/16), dim3(256), 0, stream>>>(x, We1, be1, We2, be2, z);
  mlp_kernel<64,64,32,16><<<dim3(NTOK/16), dim3(256), 0, stream>>>(z, Wd1, bd1, Wd2, bd2, x_rec);

  // 4 dynamics passes: pass 0 -> z_dyn (+ predz[0]); passes 1..3 -> predz[1..3]
  for (int p = 0; p < 4; p++) {
    for (int i = 0; i < 2; i++) {
      const float* Win_i   = Win   + (size_t)i*64*256;
      const float* Wconv_i = Wconv + (size_t)i*128*4;
      const float* bconv_i = bconv + (size_t)i*128;
      const float* Wxp_i   = Wxp   + (size_t)i*128*68;
      const float* Wdt_i   = Wdt   + (size_t)i*4*128;
      const float* bdt_i   = bdt   + (size_t)i*128;
      const float* Alog_i  = Alog  + (size_t)i*128*32;
      const float* Dp_i    = Dp    + (size_t)i*128;
      const float* Wout_i  = Wout  + (size_t)i*128*64;
      const float* zs = (i == 0) ? z : nullptr;   // block 0 reads windowed z/predz directly
      pre_kernel <<<dim3(512), dim3(256), 0, stream>>>(cur, zs, predz, p,
                                                       Win_i, Wconv_i, bconv_i, Wxp_i, Wdt_i, bdt_i,
                                                       xi, resg, dd, Bb, Cb);
      scan1_kernel<<<dim3(4096), dim3(128), 0, stream>>>(dd, Bb, Alog_i, hend, hdec);
      scan2_kernel<<<dim3(128), dim3(256), 0, stream>>>(hend, hdec, h0);
      scan3_kernel<<<dim3(4096), dim3(128), 0, stream>>>(dd, Bb, Cb, Alog_i, h0, ys);
      post_kernel<<<dim3(512), dim3(256), 0, stream>>>(ys, xi, resg, Dp_i, Wout_i,
                                                       zs, predz, p, cur);
    }
    if (p == 0)
      ln_kernel<<<dim3(NTOK/4), dim3(256), 0, stream>>>(cur, gamma, beta, zdyn, predz, 0, 1);
    else
      ln_kernel<<<dim3(2), dim3(256), 0, stream>>>(cur, gamma, beta, (float*)nullptr, predz, p, 0);
  }

  // x_dyn = dec(z_dyn); x_pred = dec(predz)
  mlp_kernel<64,64,32,16><<<dim3(NTOK/16), dim3(256), 0, stream>>>(zdyn, Wd1, bd1, Wd2, bd2, x_dyn);
  mlp_kernel<64,64,32,16><<<dim3(2), dim3(256), 0, stream>>>(predz, Wd1, bd1, Wd2, bd2, x_pred);
}

// Round 5
// 621.076 us; speedup vs baseline: 4.0108x; 1.1652x over previous
//
#include <hip/hip_runtime.h>

#define BSZ 8
#define TLEN 1024
#define DIN 32
#define DM 64
#define DI 128
#define DS 32
#define NTOK (BSZ*TLEN)
#define NCHUNK 16
#define CLEN 64

__device__ __forceinline__ float siluf(float x) { return x / (1.f + expf(-x)); }
__device__ __forceinline__ float softplusf(float x) { return (x > 20.f) ? x : log1pf(expf(x)); }

// ---------------- per-token MLP: relu(x@W1+b1)@W2+b2 ----------------
template<int IN, int H, int OUT, int TT>
__global__ __launch_bounds__(256) void mlp_kernel(
    const float* __restrict__ x, const float* __restrict__ W1, const float* __restrict__ b1,
    const float* __restrict__ W2, const float* __restrict__ b2, float* __restrict__ out)
{
  __shared__ float s_x[TT*IN];
  __shared__ float s_h[TT*H];
  const int tid = threadIdx.x;
  const int t0 = blockIdx.x * TT;
  for (int i = tid; i < TT*IN; i += 256) s_x[i] = x[t0*IN + i];
  __syncthreads();
  #pragma unroll
  for (int u = 0; u < (TT*H + 255)/256; u++) {
    int i = tid + u*256;
    if (i < TT*H) {
      int t = i / H, j = i % H;
      float acc = b1[j];
      for (int k = 0; k < IN; k++) acc = fmaf(s_x[t*IN + k], W1[k*H + j], acc);
      s_h[i] = fmaxf(acc, 0.f);
    }
  }
  __syncthreads();
  #pragma unroll
  for (int u = 0; u < (TT*OUT + 255)/256; u++) {
    int i = tid + u*256;
    if (i < TT*OUT) {
      int t = i / OUT, c = i % OUT;
      float acc = b2[c];
      for (int k = 0; k < H; k++) acc = fmaf(s_h[t*H + k], W2[k*OUT + c], acc);
      out[(t0 + t)*OUT + c] = acc;
    }
  }
}

// ---------------- pre: window -> xz GEMM -> conv/silu in registers -> xproj -> dt ----------------
// 8 tokens/block (+3 halo), 1024 blocks (4/CU -> 16 waves/CU), ~7KB LDS.
__global__ __launch_bounds__(256,4) void pre_kernel(
    const float* __restrict__ inbuf, const float* __restrict__ zsrc, const float* __restrict__ pzsrc, int shift,
    const float* __restrict__ Win, const float* __restrict__ Wconv, const float* __restrict__ bconv,
    const float* __restrict__ Wxproj, const float* __restrict__ Wdt, const float* __restrict__ bdt,
    float* __restrict__ xibuf, float* __restrict__ resgbuf,
    float2* __restrict__ ddbuf, float* __restrict__ Bbuf, float* __restrict__ Cbuf)
{
  __shared__ float s_in[11*64];
  __shared__ float s_xi[8*128];
  __shared__ float s_dtr[8*4];
  const int tid = threadIdx.x;
  const int b  = blockIdx.x >> 7;
  const int t0 = (blockIdx.x & 127) * 8;

  for (int i = tid; i < 11*64; i += 256) {
    int r = i >> 6, cc = i & 63;
    int tg = t0 - 3 + r;
    float v = 0.f;
    if (tg >= 0) {
      if (zsrc) {
        int st = tg + shift;
        v = (st < TLEN) ? zsrc[(b*TLEN + st)*DM + cc] : pzsrc[(b*4 + (st - TLEN))*DM + cc];
      } else {
        v = inbuf[(b*TLEN + tg)*DM + cc];
      }
    }
    s_in[i] = v;
  }
  __syncthreads();
  // xz GEMM: thread owns column tid; 11 token-rows in registers. Fully unrolled k.
  float acc[11];
  #pragma unroll
  for (int r = 0; r < 11; r++) acc[r] = 0.f;
  #pragma unroll
  for (int k4 = 0; k4 < 16; k4++) {
    float w0 = Win[(k4*4+0)*256 + tid];
    float w1 = Win[(k4*4+1)*256 + tid];
    float w2 = Win[(k4*4+2)*256 + tid];
    float w3 = Win[(k4*4+3)*256 + tid];
    #pragma unroll
    for (int r = 0; r < 11; r++) {
      float4 xv = *(const float4*)&s_in[r*64 + k4*4];
      acc[r] = fmaf(xv.x, w0, acc[r]);
      acc[r] = fmaf(xv.y, w1, acc[r]);
      acc[r] = fmaf(xv.z, w2, acc[r]);
      acc[r] = fmaf(xv.w, w3, acc[r]);
    }
  }
  // conv (K=4) + silu entirely in registers
  if (tid < 128) {
    float4 wc = *(const float4*)&Wconv[tid*4];
    float bc = bconv[tid];
    #pragma unroll
    for (int tau = 0; tau < 8; tau++) {
      float v = bc;
      v = fmaf(acc[tau+0], wc.x, v);
      v = fmaf(acc[tau+1], wc.y, v);
      v = fmaf(acc[tau+2], wc.z, v);
      v = fmaf(acc[tau+3], wc.w, v);
      float xiv = siluf(v);
      s_xi[tau*128 + tid] = xiv;
      xibuf[(b*TLEN + t0 + tau)*DI + tid] = xiv;
    }
  } else {
    int d = tid - 128;
    #pragma unroll
    for (int tau = 0; tau < 8; tau++)
      resgbuf[(b*TLEN + t0 + tau)*DI + d] = siluf(acc[tau+3]);
  }
  __syncthreads();
  // xproj B/C cols: wave wv -> tokens wv*2, wv*2+1; lane c -> proj col 4+c
  {
    const int wv = tid >> 6, c = tid & 63;
    float a0 = 0.f, a1 = 0.f;
    const float4* x0 = (const float4*)&s_xi[(wv*2+0)*128];
    const float4* x1 = (const float4*)&s_xi[(wv*2+1)*128];
    #pragma unroll 4
    for (int k4 = 0; k4 < 32; k4++) {
      float wq0 = Wxproj[(k4*4+0)*68 + 4 + c];
      float wq1 = Wxproj[(k4*4+1)*68 + 4 + c];
      float wq2 = Wxproj[(k4*4+2)*68 + 4 + c];
      float wq3 = Wxproj[(k4*4+3)*68 + 4 + c];
      float4 v0 = x0[k4], v1 = x1[k4];
      a0 = fmaf(v0.x,wq0, fmaf(v0.y,wq1, fmaf(v0.z,wq2, fmaf(v0.w,wq3, a0))));
      a1 = fmaf(v1.x,wq0, fmaf(v1.y,wq1, fmaf(v1.z,wq2, fmaf(v1.w,wq3, a1))));
    }
    int tb = b*TLEN + t0 + wv*2;
    if (c < 32) {
      Bbuf[(tb+0)*DS + c] = a0; Bbuf[(tb+1)*DS + c] = a1;
    } else {
      int cc = c - 32;
      Cbuf[(tb+0)*DS + cc] = a0; Cbuf[(tb+1)*DS + cc] = a1;
    }
  }
  // dtr cols (4 per token), threads 0..31
  if (tid < 32) {
    int tau = tid >> 2, cc = tid & 3;
    float a = 0.f;
    const float4* xx = (const float4*)&s_xi[tau*128];
    #pragma unroll 4
    for (int k4 = 0; k4 < 32; k4++) {
      float4 v = xx[k4];
      a = fmaf(v.x, Wxproj[(k4*4+0)*68 + cc], a);
      a = fmaf(v.y, Wxproj[(k4*4+1)*68 + cc], a);
      a = fmaf(v.z, Wxproj[(k4*4+2)*68 + cc], a);
      a = fmaf(v.w, Wxproj[(k4*4+3)*68 + cc], a);
    }
    s_dtr[tau*4 + cc] = a;
  }
  __syncthreads();
  // dt = softplus(dtr @ Wdt + bdt); dd = (dt, dt*xi)
  #pragma unroll
  for (int u = 0; u < 4; u++) {
    int i = tid + u*256;
    int tau = i >> 7, d = i & 127;
    float a = bdt[d];
    #pragma unroll
    for (int r = 0; r < 4; r++) a = fmaf(s_dtr[tau*4 + r], Wdt[r*128 + d], a);
    float dtv = softplusf(a);
    ddbuf[(b*TLEN + t0 + tau)*DI + d] = make_float2(dtv, dtv * s_xi[i]);
  }
}

// B/C chunk swizzle: rows s,s+8,s+16,s+24 of a stride-68 [32][68] tile share bank
// groups (68*8 == 0 mod 32) -> 8-way conflict on b128 reads. XOR the float4-chunk
// index with ((s>>3)&3)<<1: the 4 colliding row-classes land on distinct 4-bank
// groups -> <=2-way. (bit0 of the swizzle is 0, so chunk pairs 2j/2j+1 stay adjacent.)
#define BSWZ(row3) (((row3)&3)<<1)

// ---------------- scan phase 1: per-chunk local scan from h=0 ----------------
__global__ __launch_bounds__(128) void scan1_kernel(
    const float2* __restrict__ ddbuf, const float* __restrict__ Bbuf,
    const float* __restrict__ Alog, float* __restrict__ hend, float* __restrict__ hdec)
{
  __shared__ float2 s_dd[4][CLEN];
  __shared__ float  s_Bt[32][68];
  const int tid = threadIdx.x;
  const int ch = tid >> 5, s = tid & 31;
  const int dg = blockIdx.x & 31;
  const int c  = (blockIdx.x >> 5) & 15;
  const int b  = blockIdx.x >> 9;
  const int d0 = dg * 4;
  const float A = -__expf(Alog[(d0 + ch)*DS + s]);
  const float2* ddg = ddbuf + (size_t)(b*TLEN + c*CLEN)*DI + d0;
  const float*  Bg  = Bbuf  + (size_t)(b*TLEN + c*CLEN)*DS;
  {
    int t = tid >> 1, half = tid & 1;
    float4 rdd = *(const float4*)((const float*)(ddg + (size_t)t*DI) + half*4);
    s_dd[2*half+0][t] = make_float2(rdd.x, rdd.y);
    s_dd[2*half+1][t] = make_float2(rdd.z, rdd.w);
    #pragma unroll
    for (int j = 0; j < 4; j++) {
      int q = tid + 128*j; int tt = q >> 3, k4 = q & 7;
      float4 rB = *(const float4*)(Bg + tt*DS + k4*4);
      int cp = (((tt>>2) ^ BSWZ(k4>>1)) << 2) + (tt & 3);
      s_Bt[k4*4+0][cp] = rB.x; s_Bt[k4*4+1][cp] = rB.y;
      s_Bt[k4*4+2][cp] = rB.z; s_Bt[k4*4+3][cp] = rB.w;
    }
  }
  __syncthreads();
  float h = 0.f, dts = 0.f;
  const float4* dd4 = (const float4*)&s_dd[ch][0];
  const float4* bt4 = (const float4*)&s_Bt[s][0];
  const int swr = BSWZ(s>>3);
  #pragma unroll
  for (int j = 0; j < 8; j++) {
    float4 e0 = dd4[4*j+0], e1 = dd4[4*j+1], e2 = dd4[4*j+2], e3 = dd4[4*j+3];
    float4 bb0 = bt4[(2*j)^swr], bb1 = bt4[(2*j+1)^swr];
    h = fmaf(__expf(e0.x*A), h, e0.y*bb0.x);
    h = fmaf(__expf(e0.z*A), h, e0.w*bb0.y);
    h = fmaf(__expf(e1.x*A), h, e1.y*bb0.z);
    h = fmaf(__expf(e1.z*A), h, e1.w*bb0.w);
    h = fmaf(__expf(e2.x*A), h, e2.y*bb1.x);
    h = fmaf(__expf(e2.z*A), h, e2.w*bb1.y);
    h = fmaf(__expf(e3.x*A), h, e3.y*bb1.z);
    h = fmaf(__expf(e3.z*A), h, e3.w*bb1.w);
    dts += (e0.x + e0.z) + (e1.x + e1.z) + (e2.x + e2.z) + (e3.x + e3.z);
  }
  int o = ((b*NCHUNK + c)*DI + d0 + ch)*DS + s;
  hend[o] = h;
  hdec[o] = __expf(A*dts);
}

// ---------------- scan phase 2: combine 16 chunks -> per-chunk initial h0 ----------------
__global__ __launch_bounds__(256) void scan2_kernel(
    const float* __restrict__ hend, const float* __restrict__ hdec, float* __restrict__ h0buf)
{
  int idx = blockIdx.x*256 + threadIdx.x;  // (b, d, s)
  int b = idx >> 12, rem = idx & 4095;
  float h = 0.f;
  #pragma unroll
  for (int c = 0; c < NCHUNK; c++) {
    int o = (b*NCHUNK + c)*4096 + rem;
    h0buf[o] = h;
    h = fmaf(hdec[o], h, hend[o]);
  }
}

// ---------------- scan phase 3: rescan chunk from h0, emit y ----------------
// s_p halved (two 32-step y-passes), stride 33 + scalar stores: conflict-free.
// LDS 36KB -> 4 blocks/CU.
__global__ __launch_bounds__(128) void scan3_kernel(
    const float2* __restrict__ ddbuf, const float* __restrict__ Bbuf, const float* __restrict__ Cbuf,
    const float* __restrict__ Alog, const float* __restrict__ h0buf, float* __restrict__ ysbuf)
{
  __shared__ float2 s_dd[4][CLEN];
  __shared__ float  s_Bt[32][68];
  __shared__ float  s_Ct[32][68];
  __shared__ float  s_p[128][33];
  const int tid = threadIdx.x;
  const int ch = tid >> 5, s = tid & 31;
  const int dg = blockIdx.x & 31;
  const int c  = (blockIdx.x >> 5) & 15;
  const int b  = blockIdx.x >> 9;
  const int d0 = dg * 4;
  const float A = -__expf(Alog[(d0 + ch)*DS + s]);
  const float2* ddg = ddbuf + (size_t)(b*TLEN + c*CLEN)*DI + d0;
  const float*  Bg  = Bbuf  + (size_t)(b*TLEN + c*CLEN)*DS;
  const float*  Cg  = Cbuf  + (size_t)(b*TLEN + c*CLEN)*DS;
  {
    int t = tid >> 1, half = tid & 1;
    float4 rdd = *(const float4*)((const float*)(ddg + (size_t)t*DI) + half*4);
    s_dd[2*half+0][t] = make_float2(rdd.x, rdd.y);
    s_dd[2*half+1][t] = make_float2(rdd.z, rdd.w);
    #pragma unroll
    for (int j = 0; j < 4; j++) {
      int q = tid + 128*j; int tt = q >> 3, k4 = q & 7;
      float4 rB = *(const float4*)(Bg + tt*DS + k4*4);
      float4 rC = *(const float4*)(Cg + tt*DS + k4*4);
      int cp = (((tt>>2) ^ BSWZ(k4>>1)) << 2) + (tt & 3);
      s_Bt[k4*4+0][cp] = rB.x; s_Bt[k4*4+1][cp] = rB.y;
      s_Bt[k4*4+2][cp] = rB.z; s_Bt[k4*4+3][cp] = rB.w;
      s_Ct[k4*4+0][cp] = rC.x; s_Ct[k4*4+1][cp] = rC.y;
      s_Ct[k4*4+2][cp] = rC.z; s_Ct[k4*4+3][cp] = rC.w;
    }
  }
  __syncthreads();
  float h = h0buf[((b*NCHUNK + c)*DI + d0 + ch)*DS + s];
  const float4* dd4 = (const float4*)&s_dd[ch][0];
  const float4* bt4 = (const float4*)&s_Bt[s][0];
  const float4* ct4 = (const float4*)&s_Ct[s][0];
  const int swr = BSWZ(s>>3);
  float* pr = &s_p[tid][0];
  #pragma unroll
  for (int half = 0; half < 2; half++) {
    #pragma unroll
    for (int j = 0; j < 4; j++) {
      const int jj = half*4 + j;
      float4 e0 = dd4[4*jj+0], e1 = dd4[4*jj+1], e2 = dd4[4*jj+2], e3 = dd4[4*jj+3];
      float4 bb0 = bt4[(2*jj)^swr], bb1 = bt4[(2*jj+1)^swr];
      float4 cc0 = ct4[(2*jj)^swr], cc1 = ct4[(2*jj+1)^swr];
      h = fmaf(__expf(e0.x*A), h, e0.y*bb0.x); pr[8*j+0] = h*cc0.x;
      h = fmaf(__expf(e0.z*A), h, e0.w*bb0.y); pr[8*j+1] = h*cc0.y;
      h = fmaf(__expf(e1.x*A), h, e1.y*bb0.z); pr[8*j+2] = h*cc0.z;
      h = fmaf(__expf(e1.z*A), h, e1.w*bb0.w); pr[8*j+3] = h*cc0.w;
      h = fmaf(__expf(e2.x*A), h, e2.y*bb1.x); pr[8*j+4] = h*cc1.x;
      h = fmaf(__expf(e2.z*A), h, e2.w*bb1.y); pr[8*j+5] = h*cc1.y;
      h = fmaf(__expf(e3.x*A), h, e3.y*bb1.z); pr[8*j+6] = h*cc1.z;
      h = fmaf(__expf(e3.z*A), h, e3.w*bb1.w); pr[8*j+7] = h*cc1.w;
    }
    __syncthreads();
    {
      const int ch2 = tid & 3;
      const int tq  = tid >> 2;
      float a = 0.f;
      #pragma unroll
      for (int s2 = 0; s2 < 32; s2++) a += s_p[ch2*32 + s2][tq];
      ysbuf[(b*TLEN + c*CLEN + half*32 + tq)*DI + d0 + ch2] = a;
    }
    __syncthreads();
  }
}

// ---------------- post: y = (ys + xi*Dp)*silu_gate; out = (window-base or +=) y @ Wout ----------------
// 8 tokens/block, 1024 blocks.
__global__ __launch_bounds__(256,4) void post_kernel(
    const float* __restrict__ ysbuf, const float* __restrict__ xibuf, const float* __restrict__ resgbuf,
    const float* __restrict__ Dp, const float* __restrict__ Wout,
    const float* __restrict__ zsrc, const float* __restrict__ pzsrc, int shift,
    float* __restrict__ outbuf)
{
  __shared__ float s_y[8*128];
  const int tid = threadIdx.x;
  const int b  = blockIdx.x >> 7;
  const int t0 = (blockIdx.x & 127) * 8;
  #pragma unroll
  for (int u = 0; u < 4; u++) {
    int i = tid + u*256;
    int g = (b*TLEN + t0)*DI + i;
    s_y[i] = (ysbuf[g] + xibuf[g]*Dp[i & 127]) * resgbuf[g];
  }
  __syncthreads();
  #pragma unroll
  for (int u = 0; u < 2; u++) {
    int i = tid + u*256;
    int tau = i >> 6, c = i & 63;
    float a = 0.f;
    const float4* yy = (const float4*)&s_y[tau*128];
    #pragma unroll 4
    for (int k4 = 0; k4 < 32; k4++) {
      float4 v = yy[k4];
      a = fmaf(v.x, Wout[(k4*4+0)*64 + c], a);
      a = fmaf(v.y, Wout[(k4*4+1)*64 + c], a);
      a = fmaf(v.z, Wout[(k4*4+2)*64 + c], a);
      a = fmaf(v.w, Wout[(k4*4+3)*64 + c], a);
    }
    int g = (b*TLEN + t0 + tau)*DM + c;
    float base;
    if (zsrc) {
      int st = t0 + tau + shift;
      base = (st < TLEN) ? zsrc[(b*TLEN + st)*DM + c] : pzsrc[(b*4 + (st - TLEN))*DM + c];
    } else {
      base = outbuf[g];
    }
    outbuf[g] = base + a;
  }
}

// ---------------- layernorm over DM=64 per token ----------------
__global__ __launch_bounds__(256) void ln_kernel(
    const float* __restrict__ src, const float* __restrict__ g, const float* __restrict__ be,
    float* __restrict__ dst, float* __restrict__ predz, int slot, int full)
{
  int wid  = (blockIdx.x * blockDim.x + threadIdx.x) >> 6;
  int lane = threadIdx.x & 63;
  int token, b;
  if (full) { token = wid; if (token >= NTOK) return; b = token >> 10; }
  else      { b = wid; if (b >= BSZ) return; token = b*TLEN + (TLEN-1); }
  float v = src[token*DM + lane];
  float sum = v;
  #pragma unroll
  for (int m = 1; m < 64; m <<= 1) sum += __shfl_xor(sum, m);
  float mean = sum * (1.f/64.f);
  float dv = v - mean;
  float vs = dv*dv;
  #pragma unroll
  for (int m = 1; m < 64; m <<= 1) vs += __shfl_xor(vs, m);
  float var = vs * (1.f/64.f);
  float o = dv * rsqrtf(var + 1e-5f) * g[lane] + be[lane];
  if (dst) dst[token*DM + lane] = o;
  if (predz && ((token & (TLEN-1)) == TLEN-1)) predz[(b*4 + slot)*DM + lane] = o;
}

extern "C" void kernel_launch(void* const* d_in, const int* in_sizes, int n_in,
                              void* d_out, int out_size, void* d_ws, size_t ws_size,
                              hipStream_t stream)
{
  (void)in_sizes; (void)n_in; (void)out_size; (void)ws_size;
  const float* x     = (const float*)d_in[0];
  const float* We1   = (const float*)d_in[1];
  const float* be1   = (const float*)d_in[2];
  const float* We2   = (const float*)d_in[3];
  const float* be2   = (const float*)d_in[4];
  const float* Wd1   = (const float*)d_in[5];
  const float* bd1   = (const float*)d_in[6];
  const float* Wd2   = (const float*)d_in[7];
  const float* bd2   = (const float*)d_in[8];
  const float* Win   = (const float*)d_in[9];
  const float* Wconv = (const float*)d_in[10];
  const float* bconv = (const float*)d_in[11];
  const float* Wxp   = (const float*)d_in[12];
  const float* Wdt   = (const float*)d_in[13];
  const float* bdt   = (const float*)d_in[14];
  const float* Alog  = (const float*)d_in[15];
  const float* Dp    = (const float*)d_in[16];
  const float* Wout  = (const float*)d_in[17];
  const float* gamma = (const float*)d_in[18];
  const float* beta  = (const float*)d_in[19];

  float* o      = (float*)d_out;
  float* x_rec  = o;                 // 8*1024*32
  float* x_dyn  = o + 262144;        // 8*1024*32
  float* x_pred = o + 524288;        // 8*4*32
  float* z      = o + 525312;        // 8*1024*64
  float* zdyn   = o + 1049600;       // 8*1024*64

  float* w     = (float*)d_ws;
  float* cur   = w;                  // 524288
  float* xi    = cur  + 524288;      // 1048576
  float* resg  = xi   + 1048576;     // 1048576
  float2* dd   = (float2*)(resg + 1048576);  // 1048576 float2
  float* Bb    = resg + 1048576 + 2097152;   // 262144
  float* Cb    = Bb   + 262144;      // 262144
  float* ys    = Cb   + 262144;      // 1048576
  float* predz = ys   + 1048576;     // 2048
  float* hend  = predz + 2048;       // 524288
  float* hdec  = hend + 524288;      // 524288
  float* h0    = hdec + 524288;      // 524288

  // encoder: z = mlp(x);  x_rec = dec(z)
  mlp_kernel<32,64,64,16><<<dim3(NTOK/16), dim3(256), 0, stream>>>(x, We1, be1, We2, be2, z);
  mlp_kernel<64,64,32,16><<<dim3(NTOK/16), dim3(256), 0, stream>>>(z, Wd1, bd1, Wd2, bd2, x_rec);

  // 4 dynamics passes: pass 0 -> z_dyn (+ predz[0]); passes 1..3 -> predz[1..3]
  for (int p = 0; p < 4; p++) {
    for (int i = 0; i < 2; i++) {
      const float* Win_i   = Win   + (size_t)i*64*256;
      const float* Wconv_i = Wconv + (size_t)i*128*4;
      const float* bconv_i = bconv + (size_t)i*128;
      const float* Wxp_i   = Wxp   + (size_t)i*128*68;
      const float* Wdt_i   = Wdt   + (size_t)i*4*128;
      const float* bdt_i   = bdt   + (size_t)i*128;
      const float* Alog_i  = Alog  + (size_t)i*128*32;
      const float* Dp_i    = Dp    + (size_t)i*128;
      const float* Wout_i  = Wout  + (size_t)i*128*64;
      const float* zs = (i == 0) ? z : nullptr;   // block 0 reads windowed z/predz directly
      pre_kernel <<<dim3(1024), dim3(256), 0, stream>>>(cur, zs, predz, p,
                                                        Win_i, Wconv_i, bconv_i, Wxp_i, Wdt_i, bdt_i,
                                                        xi, resg, dd, Bb, Cb);
      scan1_kernel<<<dim3(4096), dim3(128), 0, stream>>>(dd, Bb, Alog_i, hend, hdec);
      scan2_kernel<<<dim3(128), dim3(256), 0, stream>>>(hend, hdec, h0);
      scan3_kernel<<<dim3(4096), dim3(128), 0, stream>>>(dd, Bb, Cb, Alog_i, h0, ys);
      post_kernel<<<dim3(1024), dim3(256), 0, stream>>>(ys, xi, resg, Dp_i, Wout_i,
                                                        zs, predz, p, cur);
    }
    if (p == 0)
      ln_kernel<<<dim3(NTOK/4), dim3(256), 0, stream>>>(cur, gamma, beta, zdyn, predz, 0, 1);
    else
      ln_kernel<<<dim3(2), dim3(256), 0, stream>>>(cur, gamma, beta, (float*)nullptr, predz, p, 0);
  }

  // x_dyn = dec(z_dyn); x_pred = dec(predz)
  mlp_kernel<64,64,32,16><<<dim3(NTOK/16), dim3(256), 0, stream>>>(zdyn, Wd1, bd1, Wd2, bd2, x_dyn);
  mlp_kernel<64,64,32,16><<<dim3(2), dim3(256), 0, stream>>>(predz, Wd1, bd1, Wd2, bd2, x_pred);
}

// Round 6
// 580.141 us; speedup vs baseline: 4.2938x; 1.0706x over previous
//
#include <hip/hip_runtime.h>

#define BSZ 8
#define TLEN 1024
#define DIN 32
#define DM 64
#define DI 128
#define DS 32
#define NTOK (BSZ*TLEN)
#define NCHUNK 16
#define CLEN 64

__device__ __forceinline__ float siluf(float x) { return x / (1.f + expf(-x)); }
__device__ __forceinline__ float softplusf(float x) { return (x > 20.f) ? x : log1pf(expf(x)); }

// ---------------- per-token MLP: relu(x@W1+b1)@W2+b2 ----------------
// Stage-1 x reads are wave-uniform (t = i/H, H=64) -> direct global scalar loads, no s_x.
template<int IN, int H, int OUT, int TT>
__global__ __launch_bounds__(256) void mlp_kernel(
    const float* __restrict__ x, const float* __restrict__ W1, const float* __restrict__ b1,
    const float* __restrict__ W2, const float* __restrict__ b2, float* __restrict__ out)
{
  __shared__ float s_h[TT*H];
  const int tid = threadIdx.x;
  const int t0 = blockIdx.x * TT;
  #pragma unroll
  for (int u = 0; u < (TT*H + 255)/256; u++) {
    int i = tid + u*256;
    if (i < TT*H) {
      int t = i / H, j = i % H;
      const float* xr = x + (size_t)(t0 + t)*IN;   // uniform per wave
      float acc = b1[j];
      #pragma unroll
      for (int k4 = 0; k4 < IN/4; k4++) {
        float4 xv = *(const float4*)(xr + k4*4);
        acc = fmaf(xv.x, W1[(k4*4+0)*H + j], acc);
        acc = fmaf(xv.y, W1[(k4*4+1)*H + j], acc);
        acc = fmaf(xv.z, W1[(k4*4+2)*H + j], acc);
        acc = fmaf(xv.w, W1[(k4*4+3)*H + j], acc);
      }
      s_h[i] = fmaxf(acc, 0.f);
    }
  }
  __syncthreads();
  #pragma unroll
  for (int u = 0; u < (TT*OUT + 255)/256; u++) {
    int i = tid + u*256;
    if (i < TT*OUT) {
      int t = i / OUT, c = i % OUT;
      float acc = b2[c];
      const float4* hh = (const float4*)&s_h[t*H];
      #pragma unroll
      for (int k4 = 0; k4 < H/4; k4++) {
        float4 hv = hh[k4];
        acc = fmaf(hv.x, W2[(k4*4+0)*OUT + c], acc);
        acc = fmaf(hv.y, W2[(k4*4+1)*OUT + c], acc);
        acc = fmaf(hv.z, W2[(k4*4+2)*OUT + c], acc);
        acc = fmaf(hv.w, W2[(k4*4+3)*OUT + c], acc);
      }
      out[(size_t)(t0 + t)*OUT + c] = acc;
    }
  }
}

// ---------------- fused decoder: x_dyn = dec(zdyn) [512 blocks] + x_pred = dec(predz) [2 blocks] ----
__global__ __launch_bounds__(256) void dec2_kernel(
    const float* __restrict__ za, const float* __restrict__ zb,
    const float* __restrict__ W1, const float* __restrict__ b1,
    const float* __restrict__ W2, const float* __restrict__ b2,
    float* __restrict__ outa, float* __restrict__ outb)
{
  __shared__ float s_h[16*64];
  const int tid = threadIdx.x;
  const float* src; float* dst; int t0;
  if (blockIdx.x < 512) { src = za; dst = outa; t0 = blockIdx.x * 16; }
  else                  { src = zb; dst = outb; t0 = (blockIdx.x - 512) * 16; }
  #pragma unroll
  for (int u = 0; u < 4; u++) {
    int i = tid + u*256;
    int t = i >> 6, j = i & 63;
    const float* xr = src + (size_t)(t0 + t)*64;
    float acc = b1[j];
    #pragma unroll
    for (int k4 = 0; k4 < 16; k4++) {
      float4 xv = *(const float4*)(xr + k4*4);
      acc = fmaf(xv.x, W1[(k4*4+0)*64 + j], acc);
      acc = fmaf(xv.y, W1[(k4*4+1)*64 + j], acc);
      acc = fmaf(xv.z, W1[(k4*4+2)*64 + j], acc);
      acc = fmaf(xv.w, W1[(k4*4+3)*64 + j], acc);
    }
    s_h[i] = fmaxf(acc, 0.f);
  }
  __syncthreads();
  #pragma unroll
  for (int u = 0; u < 2; u++) {
    int i = tid + u*256;
    int t = i >> 5, c = i & 31;
    float acc = b2[c];
    const float4* hh = (const float4*)&s_h[t*64];
    #pragma unroll
    for (int k4 = 0; k4 < 16; k4++) {
      float4 hv = hh[k4];
      acc = fmaf(hv.x, W2[(k4*4+0)*32 + c], acc);
      acc = fmaf(hv.y, W2[(k4*4+1)*32 + c], acc);
      acc = fmaf(hv.z, W2[(k4*4+2)*32 + c], acc);
      acc = fmaf(hv.w, W2[(k4*4+3)*32 + c], acc);
    }
    dst[(size_t)(t0 + t)*32 + c] = acc;
  }
}

// ---------------- pre: window -> xz GEMM (scalar-load x) -> conv/silu in regs -> xproj -> dt ----
// 8 tokens/block (+3 halo), 1024 blocks. No s_in LDS: row pointers are wave-uniform -> s_load.
__global__ __launch_bounds__(256,4) void pre_kernel(
    const float* __restrict__ inbuf, const float* __restrict__ zsrc, const float* __restrict__ pzsrc, int shift,
    const float* __restrict__ Win, const float* __restrict__ Wconv, const float* __restrict__ bconv,
    const float* __restrict__ Wxproj, const float* __restrict__ Wdt, const float* __restrict__ bdt,
    float* __restrict__ xibuf, float* __restrict__ resgbuf,
    float2* __restrict__ ddbuf, float* __restrict__ Bbuf, float* __restrict__ Cbuf)
{
  __shared__ float s_xi[8*128];
  __shared__ float s_dtr[8*4];
  const int tid = threadIdx.x;
  const int b  = blockIdx.x >> 7;
  const int t0 = (blockIdx.x & 127) * 8;

  // uniform row pointers for tokens t0-3 .. t0+7
  const float* rowp[11];
  #pragma unroll
  for (int r = 0; r < 11; r++) {
    int tg = t0 - 3 + r;
    const float* rp = inbuf;  // dummy for tg<0 (never dereferenced)
    if (tg >= 0) {
      if (zsrc) {
        int st = tg + shift;
        rp = (st < TLEN) ? zsrc + (size_t)(b*TLEN + st)*DM
                         : pzsrc + (size_t)(b*4 + (st - TLEN))*DM;
      } else {
        rp = inbuf + (size_t)(b*TLEN + tg)*DM;
      }
    }
    rowp[r] = rp;
  }

  float acc[11];
  #pragma unroll
  for (int r = 0; r < 11; r++) acc[r] = 0.f;

  if (t0 > 0) {
    #pragma unroll
    for (int k4 = 0; k4 < 16; k4++) {
      float w0 = Win[(k4*4+0)*256 + tid];
      float w1 = Win[(k4*4+1)*256 + tid];
      float w2 = Win[(k4*4+2)*256 + tid];
      float w3 = Win[(k4*4+3)*256 + tid];
      #pragma unroll
      for (int r = 0; r < 11; r++) {
        float4 xv = *(const float4*)(rowp[r] + k4*4);
        acc[r] = fmaf(xv.x, w0, acc[r]);
        acc[r] = fmaf(xv.y, w1, acc[r]);
        acc[r] = fmaf(xv.z, w2, acc[r]);
        acc[r] = fmaf(xv.w, w3, acc[r]);
      }
    }
  } else {
    // first tile: rows 0..2 are zero-padding
    #pragma unroll
    for (int k4 = 0; k4 < 16; k4++) {
      float w0 = Win[(k4*4+0)*256 + tid];
      float w1 = Win[(k4*4+1)*256 + tid];
      float w2 = Win[(k4*4+2)*256 + tid];
      float w3 = Win[(k4*4+3)*256 + tid];
      #pragma unroll
      for (int r = 3; r < 11; r++) {
        float4 xv = *(const float4*)(rowp[r] + k4*4);
        acc[r] = fmaf(xv.x, w0, acc[r]);
        acc[r] = fmaf(xv.y, w1, acc[r]);
        acc[r] = fmaf(xv.z, w2, acc[r]);
        acc[r] = fmaf(xv.w, w3, acc[r]);
      }
    }
  }

  // conv (K=4) + silu entirely in registers
  if (tid < 128) {
    float4 wc = *(const float4*)&Wconv[tid*4];
    float bc = bconv[tid];
    #pragma unroll
    for (int tau = 0; tau < 8; tau++) {
      float v = bc;
      v = fmaf(acc[tau+0], wc.x, v);
      v = fmaf(acc[tau+1], wc.y, v);
      v = fmaf(acc[tau+2], wc.z, v);
      v = fmaf(acc[tau+3], wc.w, v);
      float xiv = siluf(v);
      s_xi[tau*128 + tid] = xiv;
      xibuf[(size_t)(b*TLEN + t0 + tau)*DI + tid] = xiv;
    }
  } else {
    int d = tid - 128;
    #pragma unroll
    for (int tau = 0; tau < 8; tau++)
      resgbuf[(size_t)(b*TLEN + t0 + tau)*DI + d] = siluf(acc[tau+3]);
  }
  __syncthreads();
  // xproj B/C cols: wave wv -> tokens wv*2, wv*2+1; lane c -> proj col 4+c
  {
    const int wv = tid >> 6, c = tid & 63;
    float a0 = 0.f, a1 = 0.f;
    const float4* x0 = (const float4*)&s_xi[(wv*2+0)*128];
    const float4* x1 = (const float4*)&s_xi[(wv*2+1)*128];
    #pragma unroll 4
    for (int k4 = 0; k4 < 32; k4++) {
      float wq0 = Wxproj[(k4*4+0)*68 + 4 + c];
      float wq1 = Wxproj[(k4*4+1)*68 + 4 + c];
      float wq2 = Wxproj[(k4*4+2)*68 + 4 + c];
      float wq3 = Wxproj[(k4*4+3)*68 + 4 + c];
      float4 v0 = x0[k4], v1 = x1[k4];
      a0 = fmaf(v0.x,wq0, fmaf(v0.y,wq1, fmaf(v0.z,wq2, fmaf(v0.w,wq3, a0))));
      a1 = fmaf(v1.x,wq0, fmaf(v1.y,wq1, fmaf(v1.z,wq2, fmaf(v1.w,wq3, a1))));
    }
    int tb = b*TLEN + t0 + wv*2;
    if (c < 32) {
      Bbuf[(size_t)(tb+0)*DS + c] = a0; Bbuf[(size_t)(tb+1)*DS + c] = a1;
    } else {
      int cc = c - 32;
      Cbuf[(size_t)(tb+0)*DS + cc] = a0; Cbuf[(size_t)(tb+1)*DS + cc] = a1;
    }
  }
  // dtr cols (4 per token), threads 0..31
  if (tid < 32) {
    int tau = tid >> 2, cc = tid & 3;
    float a = 0.f;
    const float4* xx = (const float4*)&s_xi[tau*128];
    #pragma unroll 4
    for (int k4 = 0; k4 < 32; k4++) {
      float4 v = xx[k4];
      a = fmaf(v.x, Wxproj[(k4*4+0)*68 + cc], a);
      a = fmaf(v.y, Wxproj[(k4*4+1)*68 + cc], a);
      a = fmaf(v.z, Wxproj[(k4*4+2)*68 + cc], a);
      a = fmaf(v.w, Wxproj[(k4*4+3)*68 + cc], a);
    }
    s_dtr[tau*4 + cc] = a;
  }
  __syncthreads();
  // dt = softplus(dtr @ Wdt + bdt); dd = (dt, dt*xi)
  #pragma unroll
  for (int u = 0; u < 4; u++) {
    int i = tid + u*256;
    int tau = i >> 7, d = i & 127;
    float a = bdt[d];
    #pragma unroll
    for (int r = 0; r < 4; r++) a = fmaf(s_dtr[tau*4 + r], Wdt[r*128 + d], a);
    float dtv = softplusf(a);
    ddbuf[(size_t)(b*TLEN + t0 + tau)*DI + d] = make_float2(dtv, dtv * s_xi[i]);
  }
}

// B/C chunk swizzle (see r4): breaks the stride-68 8-way conflict down to <=2-way.
#define BSWZ(row3) (((row3)&3)<<1)

// ---------------- scan phase 1: per-chunk local scan from h=0; emits (h_end, decay) ----------------
__global__ __launch_bounds__(128) void scan1_kernel(
    const float2* __restrict__ ddbuf, const float* __restrict__ Bbuf,
    const float* __restrict__ Alog, float2* __restrict__ hc)
{
  __shared__ float2 s_dd[4][CLEN];
  __shared__ float  s_Bt[32][68];
  const int tid = threadIdx.x;
  const int ch = tid >> 5, s = tid & 31;
  const int dg = blockIdx.x & 31;
  const int c  = (blockIdx.x >> 5) & 15;
  const int b  = blockIdx.x >> 9;
  const int d0 = dg * 4;
  const float A = -__expf(Alog[(d0 + ch)*DS + s]);
  const float2* ddg = ddbuf + (size_t)(b*TLEN + c*CLEN)*DI + d0;
  const float*  Bg  = Bbuf  + (size_t)(b*TLEN + c*CLEN)*DS;
  {
    int t = tid >> 1, half = tid & 1;
    float4 rdd = *(const float4*)((const float*)(ddg + (size_t)t*DI) + half*4);
    s_dd[2*half+0][t] = make_float2(rdd.x, rdd.y);
    s_dd[2*half+1][t] = make_float2(rdd.z, rdd.w);
    #pragma unroll
    for (int j = 0; j < 4; j++) {
      int q = tid + 128*j; int tt = q >> 3, k4 = q & 7;
      float4 rB = *(const float4*)(Bg + tt*DS + k4*4);
      int cp = (((tt>>2) ^ BSWZ(k4>>1)) << 2) + (tt & 3);
      s_Bt[k4*4+0][cp] = rB.x; s_Bt[k4*4+1][cp] = rB.y;
      s_Bt[k4*4+2][cp] = rB.z; s_Bt[k4*4+3][cp] = rB.w;
    }
  }
  __syncthreads();
  float h = 0.f, dts = 0.f;
  const float4* dd4 = (const float4*)&s_dd[ch][0];
  const float4* bt4 = (const float4*)&s_Bt[s][0];
  const int swr = BSWZ(s>>3);
  #pragma unroll
  for (int j = 0; j < 8; j++) {
    float4 e0 = dd4[4*j+0], e1 = dd4[4*j+1], e2 = dd4[4*j+2], e3 = dd4[4*j+3];
    float4 bb0 = bt4[(2*j)^swr], bb1 = bt4[(2*j+1)^swr];
    h = fmaf(__expf(e0.x*A), h, e0.y*bb0.x);
    h = fmaf(__expf(e0.z*A), h, e0.w*bb0.y);
    h = fmaf(__expf(e1.x*A), h, e1.y*bb0.z);
    h = fmaf(__expf(e1.z*A), h, e1.w*bb0.w);
    h = fmaf(__expf(e2.x*A), h, e2.y*bb1.x);
    h = fmaf(__expf(e2.z*A), h, e2.w*bb1.y);
    h = fmaf(__expf(e3.x*A), h, e3.y*bb1.z);
    h = fmaf(__expf(e3.z*A), h, e3.w*bb1.w);
    dts += (e0.x + e0.z) + (e1.x + e1.z) + (e2.x + e2.z) + (e3.x + e3.z);
  }
  int o = ((b*NCHUNK + c)*DI + d0 + ch)*DS + s;
  hc[o] = make_float2(h, __expf(A*dts));
}

// ---------------- scan phase 3: prefix-combine + rescan chunk, emit y ----------------
// conly >= 0: process only chunk conly (grid = 8*32); else all (grid = 8*16*32).
__global__ __launch_bounds__(128) void scan3_kernel(
    const float2* __restrict__ ddbuf, const float* __restrict__ Bbuf, const float* __restrict__ Cbuf,
    const float* __restrict__ Alog, const float2* __restrict__ hc, float* __restrict__ ysbuf, int conly)
{
  __shared__ float2 s_dd[4][CLEN];
  __shared__ float  s_Bt[32][68];
  __shared__ float  s_Ct[32][68];
  __shared__ float  s_p[128][33];
  const int tid = threadIdx.x;
  const int ch = tid >> 5, s = tid & 31;
  const int dg = blockIdx.x & 31;
  const int c  = (conly >= 0) ? conly : ((blockIdx.x >> 5) & 15);
  const int b  = (conly >= 0) ? (blockIdx.x >> 5) : (blockIdx.x >> 9);
  const int d0 = dg * 4;
  const float A = -__expf(Alog[(d0 + ch)*DS + s]);
  const float2* ddg = ddbuf + (size_t)(b*TLEN + c*CLEN)*DI + d0;
  const float*  Bg  = Bbuf  + (size_t)(b*TLEN + c*CLEN)*DS;
  const float*  Cg  = Cbuf  + (size_t)(b*TLEN + c*CLEN)*DS;

  // prefix combine: h0 = scan of (hend, hdec) over chunks 0..c-1 (loads batched, chain in regs)
  const int ob = (d0 + ch)*DS + s;
  float2 v[15];
  #pragma unroll
  for (int q = 0; q < 15; q++) v[q] = hc[(size_t)(b*NCHUNK + q)*4096 + ob];

  {
    int t = tid >> 1, half = tid & 1;
    float4 rdd = *(const float4*)((const float*)(ddg + (size_t)t*DI) + half*4);
    s_dd[2*half+0][t] = make_float2(rdd.x, rdd.y);
    s_dd[2*half+1][t] = make_float2(rdd.z, rdd.w);
    #pragma unroll
    for (int j = 0; j < 4; j++) {
      int q = tid + 128*j; int tt = q >> 3, k4 = q & 7;
      float4 rB = *(const float4*)(Bg + tt*DS + k4*4);
      float4 rC = *(const float4*)(Cg + tt*DS + k4*4);
      int cp = (((tt>>2) ^ BSWZ(k4>>1)) << 2) + (tt & 3);
      s_Bt[k4*4+0][cp] = rB.x; s_Bt[k4*4+1][cp] = rB.y;
      s_Bt[k4*4+2][cp] = rB.z; s_Bt[k4*4+3][cp] = rB.w;
      s_Ct[k4*4+0][cp] = rC.x; s_Ct[k4*4+1][cp] = rC.y;
      s_Ct[k4*4+2][cp] = rC.z; s_Ct[k4*4+3][cp] = rC.w;
    }
  }
  float h = 0.f;
  #pragma unroll
  for (int q = 0; q < 15; q++)
    if (q < c) h = fmaf(v[q].y, h, v[q].x);
  __syncthreads();

  const float4* dd4 = (const float4*)&s_dd[ch][0];
  const float4* bt4 = (const float4*)&s_Bt[s][0];
  const float4* ct4 = (const float4*)&s_Ct[s][0];
  const int swr = BSWZ(s>>3);
  float* pr = &s_p[tid][0];
  #pragma unroll
  for (int half = 0; half < 2; half++) {
    #pragma unroll
    for (int j = 0; j < 4; j++) {
      const int jj = half*4 + j;
      float4 e0 = dd4[4*jj+0], e1 = dd4[4*jj+1], e2 = dd4[4*jj+2], e3 = dd4[4*jj+3];
      float4 bb0 = bt4[(2*jj)^swr], bb1 = bt4[(2*jj+1)^swr];
      float4 cc0 = ct4[(2*jj)^swr], cc1 = ct4[(2*jj+1)^swr];
      h = fmaf(__expf(e0.x*A), h, e0.y*bb0.x); pr[8*j+0] = h*cc0.x;
      h = fmaf(__expf(e0.z*A), h, e0.w*bb0.y); pr[8*j+1] = h*cc0.y;
      h = fmaf(__expf(e1.x*A), h, e1.y*bb0.z); pr[8*j+2] = h*cc0.z;
      h = fmaf(__expf(e1.z*A), h, e1.w*bb0.w); pr[8*j+3] = h*cc0.w;
      h = fmaf(__expf(e2.x*A), h, e2.y*bb1.x); pr[8*j+4] = h*cc1.x;
      h = fmaf(__expf(e2.z*A), h, e2.w*bb1.y); pr[8*j+5] = h*cc1.y;
      h = fmaf(__expf(e3.x*A), h, e3.y*bb1.z); pr[8*j+6] = h*cc1.z;
      h = fmaf(__expf(e3.z*A), h, e3.w*bb1.w); pr[8*j+7] = h*cc1.w;
    }
    __syncthreads();
    {
      const int ch2 = tid & 3;
      const int tq  = tid >> 2;
      float a = 0.f;
      #pragma unroll
      for (int s2 = 0; s2 < 32; s2++) a += s_p[ch2*32 + s2][tq];
      ysbuf[(size_t)(b*TLEN + c*CLEN + half*32 + tq)*DI + d0 + ch2] = a;
    }
    __syncthreads();
  }
}

// ---------------- post: y=(ys+xi*Dp)*gate; out = base + y@Wout; optional fused LN ----------------
// mode 0: write outbuf (cur).  mode 1: fused LN -> zdyn all tokens + predz slot 0 (no cur write).
__global__ __launch_bounds__(256,4) void post_kernel(
    const float* __restrict__ ysbuf, const float* __restrict__ xibuf, const float* __restrict__ resgbuf,
    const float* __restrict__ Dp, const float* __restrict__ Wout,
    const float* __restrict__ zsrc, const float* __restrict__ pzsrc, int shift,
    float* __restrict__ outbuf, float* __restrict__ zdyn, float* __restrict__ predz,
    const float* __restrict__ gamma, const float* __restrict__ beta, int mode)
{
  __shared__ float s_y[8*128];
  const int tid = threadIdx.x;
  const int b  = blockIdx.x >> 7;
  const int t0 = (blockIdx.x & 127) * 8;
  #pragma unroll
  for (int u = 0; u < 4; u++) {
    int i = tid + u*256;
    size_t g = (size_t)(b*TLEN + t0)*DI + i;
    s_y[i] = (ysbuf[g] + xibuf[g]*Dp[i & 127]) * resgbuf[g];
  }
  __syncthreads();
  #pragma unroll
  for (int u = 0; u < 2; u++) {
    int i = tid + u*256;
    int tau = i >> 6, c = i & 63;
    float a = 0.f;
    const float4* yy = (const float4*)&s_y[tau*128];
    #pragma unroll 4
    for (int k4 = 0; k4 < 32; k4++) {
      float4 vv = yy[k4];
      a = fmaf(vv.x, Wout[(k4*4+0)*64 + c], a);
      a = fmaf(vv.y, Wout[(k4*4+1)*64 + c], a);
      a = fmaf(vv.z, Wout[(k4*4+2)*64 + c], a);
      a = fmaf(vv.w, Wout[(k4*4+3)*64 + c], a);
    }
    size_t g = (size_t)(b*TLEN + t0 + tau)*DM + c;
    float base;
    if (zsrc) {
      int st = t0 + tau + shift;
      base = (st < TLEN) ? zsrc[(size_t)(b*TLEN + st)*DM + c] : pzsrc[(size_t)(b*4 + (st - TLEN))*DM + c];
    } else {
      base = outbuf[g];
    }
    float val = base + a;
    if (mode == 0) {
      outbuf[g] = val;
    } else {
      // wave holds one full row (64 cols) -> in-wave LN
      float sum = val;
      #pragma unroll
      for (int m = 1; m < 64; m <<= 1) sum += __shfl_xor(sum, m);
      float mean = sum * (1.f/64.f);
      float dv = val - mean;
      float vs = dv*dv;
      #pragma unroll
      for (int m = 1; m < 64; m <<= 1) vs += __shfl_xor(vs, m);
      float oln = dv * rsqrtf(vs*(1.f/64.f) + 1e-5f) * gamma[c] + beta[c];
      zdyn[g] = oln;
      if (t0 + tau == TLEN-1) predz[(size_t)(b*4 + 0)*DM + c] = oln;
    }
  }
}

// ---------------- tiny post for pred passes p>=1: last token only, fused LN -> predz[slot] ----------
__global__ __launch_bounds__(128) void tiny_post_kernel(
    const float* __restrict__ ysbuf, const float* __restrict__ xibuf, const float* __restrict__ resgbuf,
    const float* __restrict__ Dp, const float* __restrict__ Wout,
    float* __restrict__ predz, const float* __restrict__ gamma, const float* __restrict__ beta, int slot)
{
  __shared__ float s_y[128];
  const int tid = threadIdx.x;
  const int b = blockIdx.x;
  size_t g = (size_t)(b*TLEN + TLEN-1)*DI + tid;
  s_y[tid] = (ysbuf[g] + xibuf[g]*Dp[tid]) * resgbuf[g];
  __syncthreads();
  if (tid < 64) {
    float a = 0.f;
    const float4* yy = (const float4*)s_y;
    #pragma unroll 4
    for (int k4 = 0; k4 < 32; k4++) {
      float4 vv = yy[k4];
      a = fmaf(vv.x, Wout[(k4*4+0)*64 + tid], a);
      a = fmaf(vv.y, Wout[(k4*4+1)*64 + tid], a);
      a = fmaf(vv.z, Wout[(k4*4+2)*64 + tid], a);
      a = fmaf(vv.w, Wout[(k4*4+3)*64 + tid], a);
    }
    float val = predz[(size_t)(b*4 + slot-1)*DM + tid] + a;
    float sum = val;
    #pragma unroll
    for (int m = 1; m < 64; m <<= 1) sum += __shfl_xor(sum, m);
    float mean = sum * (1.f/64.f);
    float dv = val - mean;
    float vs = dv*dv;
    #pragma unroll
    for (int m = 1; m < 64; m <<= 1) vs += __shfl_xor(vs, m);
    float oln = dv * rsqrtf(vs*(1.f/64.f) + 1e-5f) * gamma[tid] + beta[tid];
    predz[(size_t)(b*4 + slot)*DM + tid] = oln;
  }
}

extern "C" void kernel_launch(void* const* d_in, const int* in_sizes, int n_in,
                              void* d_out, int out_size, void* d_ws, size_t ws_size,
                              hipStream_t stream)
{
  (void)in_sizes; (void)n_in; (void)out_size; (void)ws_size;
  const float* x     = (const float*)d_in[0];
  const float* We1   = (const float*)d_in[1];
  const float* be1   = (const float*)d_in[2];
  const float* We2   = (const float*)d_in[3];
  const float* be2   = (const float*)d_in[4];
  const float* Wd1   = (const float*)d_in[5];
  const float* bd1   = (const float*)d_in[6];
  const float* Wd2   = (const float*)d_in[7];
  const float* bd2   = (const float*)d_in[8];
  const float* Win   = (const float*)d_in[9];
  const float* Wconv = (const float*)d_in[10];
  const float* bconv = (const float*)d_in[11];
  const float* Wxp   = (const float*)d_in[12];
  const float* Wdt   = (const float*)d_in[13];
  const float* bdt   = (const float*)d_in[14];
  const float* Alog  = (const float*)d_in[15];
  const float* Dp    = (const float*)d_in[16];
  const float* Wout  = (const float*)d_in[17];
  const float* gamma = (const float*)d_in[18];
  const float* beta  = (const float*)d_in[19];

  float* o      = (float*)d_out;
  float* x_rec  = o;                 // 8*1024*32
  float* x_dyn  = o + 262144;        // 8*1024*32
  float* x_pred = o + 524288;        // 8*4*32
  float* z      = o + 525312;        // 8*1024*64
  float* zdyn   = o + 1049600;       // 8*1024*64

  float* w     = (float*)d_ws;
  float* cur   = w;                  // 524288
  float* xi    = cur  + 524288;      // 1048576
  float* resg  = xi   + 1048576;     // 1048576
  float2* dd   = (float2*)(resg + 1048576);  // 1048576 float2
  float* Bb    = resg + 1048576 + 2097152;   // 262144
  float* Cb    = Bb   + 262144;      // 262144
  float* ys    = Cb   + 262144;      // 1048576
  float* predz = ys   + 1048576;     // 2048
  float2* hc   = (float2*)(predz + 2048);    // 524288 float2

  // encoder: z = mlp(x);  x_rec = dec(z)
  mlp_kernel<32,64,64,16><<<dim3(NTOK/16), dim3(256), 0, stream>>>(x, We1, be1, We2, be2, z);
  mlp_kernel<64,64,32,16><<<dim3(NTOK/16), dim3(256), 0, stream>>>(z, Wd1, bd1, Wd2, bd2, x_rec);

  // 4 dynamics passes: pass 0 -> z_dyn (+ predz[0]); passes 1..3 -> predz[1..3]
  for (int p = 0; p < 4; p++) {
    for (int i = 0; i < 2; i++) {
      const float* Win_i   = Win   + (size_t)i*64*256;
      const float* Wconv_i = Wconv + (size_t)i*128*4;
      const float* bconv_i = bconv + (size_t)i*128;
      const float* Wxp_i   = Wxp   + (size_t)i*128*68;
      const float* Wdt_i   = Wdt   + (size_t)i*4*128;
      const float* bdt_i   = bdt   + (size_t)i*128;
      const float* Alog_i  = Alog  + (size_t)i*128*32;
      const float* Dp_i    = Dp    + (size_t)i*128;
      const float* Wout_i  = Wout  + (size_t)i*128*64;
      const float* zs = (i == 0) ? z : nullptr;   // block 0 reads windowed z/predz directly
      pre_kernel <<<dim3(1024), dim3(256), 0, stream>>>(cur, zs, predz, p,
                                                        Win_i, Wconv_i, bconv_i, Wxp_i, Wdt_i, bdt_i,
                                                        xi, resg, dd, Bb, Cb);
      scan1_kernel<<<dim3(4096), dim3(128), 0, stream>>>(dd, Bb, Alog_i, hc);
      if (i == 0) {
        scan3_kernel<<<dim3(4096), dim3(128), 0, stream>>>(dd, Bb, Cb, Alog_i, hc, ys, -1);
        post_kernel<<<dim3(1024), dim3(256), 0, stream>>>(ys, xi, resg, Dp_i, Wout_i,
                                                          zs, predz, p, cur,
                                                          (float*)nullptr, (float*)nullptr,
                                                          (const float*)nullptr, (const float*)nullptr, 0);
      } else if (p == 0) {
        scan3_kernel<<<dim3(4096), dim3(128), 0, stream>>>(dd, Bb, Cb, Alog_i, hc, ys, -1);
        post_kernel<<<dim3(1024), dim3(256), 0, stream>>>(ys, xi, resg, Dp_i, Wout_i,
                                                          (const float*)nullptr, (const float*)nullptr, p, cur,
                                                          zdyn, predz, gamma, beta, 1);
      } else {
        scan3_kernel<<<dim3(256), dim3(128), 0, stream>>>(dd, Bb, Cb, Alog_i, hc, ys, 15);
        tiny_post_kernel<<<dim3(8), dim3(128), 0, stream>>>(ys, xi, resg, Dp_i, Wout_i,
                                                            predz, gamma, beta, p);
      }
    }
  }

  // x_dyn = dec(zdyn) + x_pred = dec(predz), fused
  dec2_kernel<<<dim3(514), dim3(256), 0, stream>>>(zdyn, predz, Wd1, bd1, Wd2, bd2, x_dyn, x_pred);
}

// Round 7
// 501.954 us; speedup vs baseline: 4.9627x; 1.1558x over previous
//
#include <hip/hip_runtime.h>

#define BSZ 8
#define TLEN 1024
#define DM 64
#define DI 128
#define DS 32
#define NTOK (BSZ*TLEN)
#define NCHUNK 16
#define CLEN 64
#define GEXT 1028   // 1024 z-tokens + up to 4 predz tokens (global token axis for block-0 buffers)

__device__ __forceinline__ float siluf(float x) { return x / (1.f + expf(-x)); }
__device__ __forceinline__ float softplusf(float x) { return (x > 20.f) ? x : log1pf(expf(x)); }

// ---------------- fused encoder + reconstruction decoder ----------------
// z = relu(x@We1+be1)@We2+be2 ; x_rec = relu(z@Wd1+bd1)@Wd2+bd2
// 16 tokens/block, 512 blocks. Weight COLUMNS held in registers, reused over 4 tokens.
__global__ __launch_bounds__(256) void enc_xrec_kernel(
    const float* __restrict__ x,
    const float* __restrict__ We1, const float* __restrict__ be1,
    const float* __restrict__ We2, const float* __restrict__ be2,
    const float* __restrict__ Wd1, const float* __restrict__ bd1,
    const float* __restrict__ Wd2, const float* __restrict__ bd2,
    float* __restrict__ z, float* __restrict__ x_rec)
{
  __shared__ float s_x[16*32];
  __shared__ float s_h1[16*64];
  __shared__ float s_z[16*64];
  __shared__ float s_h2[16*64];
  const int tid = threadIdx.x;
  const int t0 = blockIdx.x * 16;
  s_x[tid]       = x[(size_t)t0*32 + tid];
  s_x[tid + 256] = x[(size_t)t0*32 + tid + 256];
  __syncthreads();
  const int j = tid & 63, tg = tid >> 6;
  { // enc stage 1
    float w[32];
    #pragma unroll
    for (int k = 0; k < 32; k++) w[k] = We1[k*64 + j];
    #pragma unroll
    for (int q = 0; q < 4; q++) {
      int t = tg*4 + q;
      float a = be1[j];
      #pragma unroll
      for (int k = 0; k < 32; k++) a = fmaf(s_x[t*32 + k], w[k], a);
      s_h1[t*64 + j] = fmaxf(a, 0.f);
    }
  }
  __syncthreads();
  { // enc stage 2 -> z
    float w[64];
    #pragma unroll
    for (int k = 0; k < 64; k++) w[k] = We2[k*64 + j];
    #pragma unroll
    for (int q = 0; q < 4; q++) {
      int t = tg*4 + q;
      float a = be2[j];
      #pragma unroll
      for (int k = 0; k < 64; k++) a = fmaf(s_h1[t*64 + k], w[k], a);
      s_z[t*64 + j] = a;
      z[(size_t)(t0 + t)*64 + j] = a;
    }
  }
  __syncthreads();
  { // dec stage 1
    float w[64];
    #pragma unroll
    for (int k = 0; k < 64; k++) w[k] = Wd1[k*64 + j];
    #pragma unroll
    for (int q = 0; q < 4; q++) {
      int t = tg*4 + q;
      float a = bd1[j];
      #pragma unroll
      for (int k = 0; k < 64; k++) a = fmaf(s_z[t*64 + k], w[k], a);
      s_h2[t*64 + j] = fmaxf(a, 0.f);
    }
  }
  __syncthreads();
  { // dec stage 2 -> x_rec
    const int c = tid & 31, tg2 = tid >> 5;
    float w[64];
    #pragma unroll
    for (int k = 0; k < 64; k++) w[k] = Wd2[k*32 + c];
    #pragma unroll
    for (int q = 0; q < 2; q++) {
      int t = tg2*2 + q;
      float a = bd2[c];
      #pragma unroll
      for (int k = 0; k < 64; k++) a = fmaf(s_h2[t*64 + k], w[k], a);
      x_rec[(size_t)(t0 + t)*32 + c] = a;
    }
  }
}

// ---------------- final decoder: x_dyn = dec(zdyn) [512 blk] + x_pred = dec(predz) [2 blk] ----
__global__ __launch_bounds__(256) void dec2_kernel(
    const float* __restrict__ za, const float* __restrict__ zb,
    const float* __restrict__ W1, const float* __restrict__ b1,
    const float* __restrict__ W2, const float* __restrict__ b2,
    float* __restrict__ outa, float* __restrict__ outb)
{
  __shared__ float s_z[16*64];
  __shared__ float s_h[16*64];
  const int tid = threadIdx.x;
  const float* src; float* dst; int t0;
  if (blockIdx.x < 512) { src = za; dst = outa; t0 = blockIdx.x * 16; }
  else                  { src = zb; dst = outb; t0 = (blockIdx.x - 512) * 16; }
  #pragma unroll
  for (int u = 0; u < 4; u++) s_z[tid + u*256] = src[(size_t)t0*64 + tid + u*256];
  __syncthreads();
  const int j = tid & 63, tg = tid >> 6;
  {
    float w[64];
    #pragma unroll
    for (int k = 0; k < 64; k++) w[k] = W1[k*64 + j];
    #pragma unroll
    for (int q = 0; q < 4; q++) {
      int t = tg*4 + q;
      float a = b1[j];
      #pragma unroll
      for (int k = 0; k < 64; k++) a = fmaf(s_z[t*64 + k], w[k], a);
      s_h[t*64 + j] = fmaxf(a, 0.f);
    }
  }
  __syncthreads();
  {
    const int c = tid & 31, tg2 = tid >> 5;
    float w[64];
    #pragma unroll
    for (int k = 0; k < 64; k++) w[k] = W2[k*32 + c];
    #pragma unroll
    for (int q = 0; q < 2; q++) {
      int t = tg2*2 + q;
      float a = b2[c];
      #pragma unroll
      for (int k = 0; k < 64; k++) a = fmaf(s_h[t*64 + k], w[k], a);
      dst[(size_t)(t0 + t)*32 + c] = a;
    }
  }
}

// ---------------- pre: window -> xz GEMM -> conv/silu in regs -> xproj -> dt ----------------
// 8 tokens/block (+3 halo), 1024 blocks. xzout!=null: also store raw xz xi-half (i=0 path).
__global__ __launch_bounds__(256,4) void pre_kernel(
    const float* __restrict__ inbuf, const float* __restrict__ zsrc, const float* __restrict__ pzsrc, int shift,
    const float* __restrict__ Win, const float* __restrict__ Wconv, const float* __restrict__ bconv,
    const float* __restrict__ Wxproj, const float* __restrict__ Wdt, const float* __restrict__ bdt,
    float* __restrict__ xibuf, float* __restrict__ resgbuf,
    float2* __restrict__ ddbuf, float* __restrict__ Bbuf, float* __restrict__ Cbuf,
    float* __restrict__ xzout, int wstride)
{
  __shared__ float s_xi[8*128];
  __shared__ float s_dtr[8*4];
  const int tid = threadIdx.x;
  const int b  = blockIdx.x >> 7;
  const int t0 = (blockIdx.x & 127) * 8;

  const float* rowp[11];
  #pragma unroll
  for (int r = 0; r < 11; r++) {
    int tg = t0 - 3 + r;
    const float* rp = inbuf;
    if (tg >= 0) {
      if (zsrc) {
        int st = tg + shift;
        rp = (st < TLEN) ? zsrc + (size_t)(b*TLEN + st)*DM
                         : pzsrc + (size_t)(b*4 + (st - TLEN))*DM;
      } else {
        rp = inbuf + (size_t)(b*TLEN + tg)*DM;
      }
    }
    rowp[r] = rp;
  }

  float acc[11];
  #pragma unroll
  for (int r = 0; r < 11; r++) acc[r] = 0.f;

  if (t0 > 0) {
    #pragma unroll
    for (int k4 = 0; k4 < 16; k4++) {
      float w0 = Win[(k4*4+0)*256 + tid];
      float w1 = Win[(k4*4+1)*256 + tid];
      float w2 = Win[(k4*4+2)*256 + tid];
      float w3 = Win[(k4*4+3)*256 + tid];
      #pragma unroll
      for (int r = 0; r < 11; r++) {
        float4 xv = *(const float4*)(rowp[r] + k4*4);
        acc[r] = fmaf(xv.x, w0, acc[r]);
        acc[r] = fmaf(xv.y, w1, acc[r]);
        acc[r] = fmaf(xv.z, w2, acc[r]);
        acc[r] = fmaf(xv.w, w3, acc[r]);
      }
    }
  } else {
    #pragma unroll
    for (int k4 = 0; k4 < 16; k4++) {
      float w0 = Win[(k4*4+0)*256 + tid];
      float w1 = Win[(k4*4+1)*256 + tid];
      float w2 = Win[(k4*4+2)*256 + tid];
      float w3 = Win[(k4*4+3)*256 + tid];
      #pragma unroll
      for (int r = 3; r < 11; r++) {
        float4 xv = *(const float4*)(rowp[r] + k4*4);
        acc[r] = fmaf(xv.x, w0, acc[r]);
        acc[r] = fmaf(xv.y, w1, acc[r]);
        acc[r] = fmaf(xv.z, w2, acc[r]);
        acc[r] = fmaf(xv.w, w3, acc[r]);
      }
    }
  }

  if (tid < 128) {
    float4 wc = *(const float4*)&Wconv[tid*4];
    float bc = bconv[tid];
    #pragma unroll
    for (int tau = 0; tau < 8; tau++) {
      float v = bc;
      v = fmaf(acc[tau+0], wc.x, v);
      v = fmaf(acc[tau+1], wc.y, v);
      v = fmaf(acc[tau+2], wc.z, v);
      v = fmaf(acc[tau+3], wc.w, v);
      float xiv = siluf(v);
      s_xi[tau*128 + tid] = xiv;
      xibuf[((size_t)b*wstride + t0 + tau)*DI + tid] = xiv;
      if (xzout) xzout[((size_t)b*wstride + t0 + tau)*128 + tid] = acc[tau+3];
    }
  } else {
    int d = tid - 128;
    #pragma unroll
    for (int tau = 0; tau < 8; tau++)
      resgbuf[((size_t)b*wstride + t0 + tau)*DI + d] = siluf(acc[tau+3]);
  }
  __syncthreads();
  {
    const int wv = tid >> 6, c = tid & 63;
    float a0 = 0.f, a1 = 0.f;
    const float4* x0 = (const float4*)&s_xi[(wv*2+0)*128];
    const float4* x1 = (const float4*)&s_xi[(wv*2+1)*128];
    #pragma unroll 4
    for (int k4 = 0; k4 < 32; k4++) {
      float wq0 = Wxproj[(k4*4+0)*68 + 4 + c];
      float wq1 = Wxproj[(k4*4+1)*68 + 4 + c];
      float wq2 = Wxproj[(k4*4+2)*68 + 4 + c];
      float wq3 = Wxproj[(k4*4+3)*68 + 4 + c];
      float4 v0 = x0[k4], v1 = x1[k4];
      a0 = fmaf(v0.x,wq0, fmaf(v0.y,wq1, fmaf(v0.z,wq2, fmaf(v0.w,wq3, a0))));
      a1 = fmaf(v1.x,wq0, fmaf(v1.y,wq1, fmaf(v1.z,wq2, fmaf(v1.w,wq3, a1))));
    }
    size_t tb = (size_t)b*wstride + t0 + wv*2;
    if (c < 32) {
      Bbuf[(tb+0)*DS + c] = a0; Bbuf[(tb+1)*DS + c] = a1;
    } else {
      int cc = c - 32;
      Cbuf[(tb+0)*DS + cc] = a0; Cbuf[(tb+1)*DS + cc] = a1;
    }
  }
  if (tid < 32) {
    int tau = tid >> 2, cc = tid & 3;
    float a = 0.f;
    const float4* xx = (const float4*)&s_xi[tau*128];
    #pragma unroll 4
    for (int k4 = 0; k4 < 32; k4++) {
      float4 v = xx[k4];
      a = fmaf(v.x, Wxproj[(k4*4+0)*68 + cc], a);
      a = fmaf(v.y, Wxproj[(k4*4+1)*68 + cc], a);
      a = fmaf(v.z, Wxproj[(k4*4+2)*68 + cc], a);
      a = fmaf(v.w, Wxproj[(k4*4+3)*68 + cc], a);
    }
    s_dtr[tau*4 + cc] = a;
  }
  __syncthreads();
  #pragma unroll
  for (int u = 0; u < 4; u++) {
    int i = tid + u*256;
    int tau = i >> 7, d = i & 127;
    float a = bdt[d];
    #pragma unroll
    for (int r = 0; r < 4; r++) a = fmaf(s_dtr[tau*4 + r], Wdt[r*128 + d], a);
    float dtv = softplusf(a);
    ddbuf[((size_t)b*wstride + t0 + tau)*DI + d] = make_float2(dtv, dtv * s_xi[i]);
  }
}

// ---------------- patch: (optional tiny_post of pass p-1) + recompute pre(i=0) for tokens
// {p, p+1, p+2, 1023+p}. 8 blocks (one per batch), 256 threads.
__global__ __launch_bounds__(256) void patch_kernel(
    int p, int do_tp,
    const float* __restrict__ ysbuf, const float* __restrict__ xi1, const float* __restrict__ resg1,
    const float* __restrict__ Dp1, const float* __restrict__ Wout1,
    const float* __restrict__ gamma, const float* __restrict__ beta,
    float* __restrict__ predz,
    float* __restrict__ xz0,
    const float* __restrict__ Win0, const float* __restrict__ Wconv0, const float* __restrict__ bconv0,
    const float* __restrict__ Wxp0, const float* __restrict__ Wdt0, const float* __restrict__ bdt0,
    float* __restrict__ xi0, float* __restrict__ resg0,
    float2* __restrict__ dd0, float* __restrict__ Bb0, float* __restrict__ Cb0)
{
  __shared__ float s_pz[64];
  __shared__ float s_y[128];
  __shared__ float s_new[256];
  __shared__ float s_xi[4][128];
  __shared__ float s_dtr[4][4];
  const int tid = threadIdx.x;
  const int b = blockIdx.x;
  const int gn = 1023 + p;   // new global token (predz[p-1])

  if (do_tp) {
    // tiny_post of pass p-1 (block i=1): predz[b][p-1] = LN(predz[b][p-2] + y_last @ Wout1)
    if (tid < 128) {
      size_t g = (size_t)(b*TLEN + TLEN-1)*DI + tid;
      s_y[tid] = (ysbuf[g] + xi1[g]*Dp1[tid]) * resg1[g];
    }
    __syncthreads();
    if (tid < 64) {
      float a = 0.f;
      #pragma unroll 4
      for (int k = 0; k < 128; k++) a = fmaf(s_y[k], Wout1[k*64 + tid], a);
      float val = predz[(size_t)(b*4 + p-2)*DM + tid] + a;
      float sum = val;
      #pragma unroll
      for (int m = 1; m < 64; m <<= 1) sum += __shfl_xor(sum, m);
      float mean = sum * (1.f/64.f);
      float dv = val - mean;
      float vs = dv*dv;
      #pragma unroll
      for (int m = 1; m < 64; m <<= 1) vs += __shfl_xor(vs, m);
      float oln = dv * rsqrtf(vs*(1.f/64.f) + 1e-5f) * gamma[tid] + beta[tid];
      predz[(size_t)(b*4 + p-1)*DM + tid] = oln;
      s_pz[tid] = oln;
    }
  } else {
    if (tid < 64) s_pz[tid] = predz[(size_t)(b*4 + p-1)*DM + tid];
  }
  __syncthreads();

  // phase 1: xz of the new token gn: s_new[col] = predz[p-1] @ Win0
  {
    float a = 0.f;
    #pragma unroll
    for (int k = 0; k < 64; k++) a = fmaf(s_pz[k], Win0[k*256 + tid], a);
    s_new[tid] = a;
  }
  __syncthreads();
  if (tid < 128) xz0[((size_t)b*GEXT + gn)*128 + tid] = s_new[tid];
  else           resg0[((size_t)b*GEXT + gn)*DI + (tid-128)] = siluf(s_new[tid]);

  // phase 2: conv + silu for 4 tokens x 128 ch
  #pragma unroll
  for (int jj = 0; jj < 2; jj++) {
    int job = tid + jj*256;
    int tok = job >> 7, d = job & 127;
    int g = (tok < 3) ? (p + tok) : gn;
    float a = bconv0[d];
    #pragma unroll
    for (int k = 0; k < 4; k++) {
      int row = g - 3 + k;
      float xv;
      if (tok < 3) xv = (row >= p) ? xz0[((size_t)b*GEXT + row)*128 + d] : 0.f;
      else         xv = (k < 3) ? xz0[((size_t)b*GEXT + row)*128 + d] : s_new[d];
      a = fmaf(xv, Wconv0[d*4 + k], a);
    }
    float xiv = siluf(a);
    s_xi[tok][d] = xiv;
    xi0[((size_t)b*GEXT + g)*DI + d] = xiv;
  }
  __syncthreads();

  // phase 3: xproj: 4 tokens x 68 cols = 272 jobs
  #pragma unroll
  for (int jj = 0; jj < 2; jj++) {
    int job = tid + jj*256;
    if (job < 272) {
      int tok = job / 68, c = job % 68;
      int g = (tok < 3) ? (p + tok) : gn;
      float a = 0.f;
      #pragma unroll 4
      for (int k = 0; k < 128; k++) a = fmaf(s_xi[tok][k], Wxp0[k*68 + c], a);
      if (c < 4)        s_dtr[tok][c] = a;
      else if (c < 36)  Bb0[((size_t)b*GEXT + g)*DS + (c - 4)]  = a;
      else              Cb0[((size_t)b*GEXT + g)*DS + (c - 36)] = a;
    }
  }
  __syncthreads();

  // phase 4: dt + dd
  #pragma unroll
  for (int jj = 0; jj < 2; jj++) {
    int job = tid + jj*256;
    int tok = job >> 7, d = job & 127;
    int g = (tok < 3) ? (p + tok) : gn;
    float a = bdt0[d];
    #pragma unroll
    for (int r = 0; r < 4; r++) a = fmaf(s_dtr[tok][r], Wdt0[r*128 + d], a);
    float dtv = softplusf(a);
    dd0[((size_t)b*GEXT + g)*DI + d] = make_float2(dtv, dtv * s_xi[tok][d]);
  }
}

// B/C chunk swizzle (r4): breaks the stride-68 8-way conflict down to <=2-way.
#define BSWZ(row3) (((row3)&3)<<1)

// ---------------- scan phase 1: per-chunk local scan from h=0; emits (h_end, decay) ----------------
__global__ __launch_bounds__(128) void scan1_kernel(
    const float2* __restrict__ ddbuf, const float* __restrict__ Bbuf,
    const float* __restrict__ Alog, float2* __restrict__ hc, int stride, int off)
{
  __shared__ float2 s_dd[4][CLEN];
  __shared__ float  s_Bt[32][68];
  const int tid = threadIdx.x;
  const int ch = tid >> 5, s = tid & 31;
  const int dg = blockIdx.x & 31;
  const int c  = (blockIdx.x >> 5) & 15;
  const int b  = blockIdx.x >> 9;
  const int d0 = dg * 4;
  const float A = -__expf(Alog[(d0 + ch)*DS + s]);
  const float2* ddg = ddbuf + ((size_t)b*stride + off + c*CLEN)*DI + d0;
  const float*  Bg  = Bbuf  + ((size_t)b*stride + off + c*CLEN)*DS;
  {
    int t = tid >> 1, half = tid & 1;
    float4 rdd = *(const float4*)((const float*)(ddg + (size_t)t*DI) + half*4);
    s_dd[2*half+0][t] = make_float2(rdd.x, rdd.y);
    s_dd[2*half+1][t] = make_float2(rdd.z, rdd.w);
    #pragma unroll
    for (int j = 0; j < 4; j++) {
      int q = tid + 128*j; int tt = q >> 3, k4 = q & 7;
      float4 rB = *(const float4*)(Bg + tt*DS + k4*4);
      int cp = (((tt>>2) ^ BSWZ(k4>>1)) << 2) + (tt & 3);
      s_Bt[k4*4+0][cp] = rB.x; s_Bt[k4*4+1][cp] = rB.y;
      s_Bt[k4*4+2][cp] = rB.z; s_Bt[k4*4+3][cp] = rB.w;
    }
  }
  __syncthreads();
  float h = 0.f, dts = 0.f;
  const float4* dd4 = (const float4*)&s_dd[ch][0];
  const float4* bt4 = (const float4*)&s_Bt[s][0];
  const int swr = BSWZ(s>>3);
  #pragma unroll
  for (int j = 0; j < 8; j++) {
    float4 e0 = dd4[4*j+0], e1 = dd4[4*j+1], e2 = dd4[4*j+2], e3 = dd4[4*j+3];
    float4 bb0 = bt4[(2*j)^swr], bb1 = bt4[(2*j+1)^swr];
    h = fmaf(__expf(e0.x*A), h, e0.y*bb0.x);
    h = fmaf(__expf(e0.z*A), h, e0.w*bb0.y);
    h = fmaf(__expf(e1.x*A), h, e1.y*bb0.z);
    h = fmaf(__expf(e1.z*A), h, e1.w*bb0.w);
    h = fmaf(__expf(e2.x*A), h, e2.y*bb1.x);
    h = fmaf(__expf(e2.z*A), h, e2.w*bb1.y);
    h = fmaf(__expf(e3.x*A), h, e3.y*bb1.z);
    h = fmaf(__expf(e3.z*A), h, e3.w*bb1.w);
    dts += (e0.x + e0.z) + (e1.x + e1.z) + (e2.x + e2.z) + (e3.x + e3.z);
  }
  int o = ((b*NCHUNK + c)*DI + d0 + ch)*DS + s;
  hc[o] = make_float2(h, __expf(A*dts));
}

// ---------------- scan phase 3: prefix-combine + rescan chunk, emit y (window-relative) ----------------
__global__ __launch_bounds__(128) void scan3_kernel(
    const float2* __restrict__ ddbuf, const float* __restrict__ Bbuf, const float* __restrict__ Cbuf,
    const float* __restrict__ Alog, const float2* __restrict__ hc, float* __restrict__ ysbuf,
    int conly, int stride, int off)
{
  __shared__ float2 s_dd[4][CLEN];
  __shared__ float  s_Bt[32][68];
  __shared__ float  s_Ct[32][68];
  __shared__ float  s_p[128][33];
  const int tid = threadIdx.x;
  const int ch = tid >> 5, s = tid & 31;
  const int dg = blockIdx.x & 31;
  const int c  = (conly >= 0) ? conly : ((blockIdx.x >> 5) & 15);
  const int b  = (conly >= 0) ? (blockIdx.x >> 5) : (blockIdx.x >> 9);
  const int d0 = dg * 4;
  const float A = -__expf(Alog[(d0 + ch)*DS + s]);
  const float2* ddg = ddbuf + ((size_t)b*stride + off + c*CLEN)*DI + d0;
  const float*  Bg  = Bbuf  + ((size_t)b*stride + off + c*CLEN)*DS;
  const float*  Cg  = Cbuf  + ((size_t)b*stride + off + c*CLEN)*DS;

  const int ob = (d0 + ch)*DS + s;
  float2 v[15];
  #pragma unroll
  for (int q = 0; q < 15; q++) v[q] = hc[(size_t)(b*NCHUNK + q)*4096 + ob];

  {
    int t = tid >> 1, half = tid & 1;
    float4 rdd = *(const float4*)((const float*)(ddg + (size_t)t*DI) + half*4);
    s_dd[2*half+0][t] = make_float2(rdd.x, rdd.y);
    s_dd[2*half+1][t] = make_float2(rdd.z, rdd.w);
    #pragma unroll
    for (int j = 0; j < 4; j++) {
      int q = tid + 128*j; int tt = q >> 3, k4 = q & 7;
      float4 rB = *(const float4*)(Bg + tt*DS + k4*4);
      float4 rC = *(const float4*)(Cg + tt*DS + k4*4);
      int cp = (((tt>>2) ^ BSWZ(k4>>1)) << 2) + (tt & 3);
      s_Bt[k4*4+0][cp] = rB.x; s_Bt[k4*4+1][cp] = rB.y;
      s_Bt[k4*4+2][cp] = rB.z; s_Bt[k4*4+3][cp] = rB.w;
      s_Ct[k4*4+0][cp] = rC.x; s_Ct[k4*4+1][cp] = rC.y;
      s_Ct[k4*4+2][cp] = rC.z; s_Ct[k4*4+3][cp] = rC.w;
    }
  }
  float h = 0.f;
  #pragma unroll
  for (int q = 0; q < 15; q++)
    if (q < c) h = fmaf(v[q].y, h, v[q].x);
  __syncthreads();

  const float4* dd4 = (const float4*)&s_dd[ch][0];
  const float4* bt4 = (const float4*)&s_Bt[s][0];
  const float4* ct4 = (const float4*)&s_Ct[s][0];
  const int swr = BSWZ(s>>3);
  float* pr = &s_p[tid][0];
  #pragma unroll
  for (int half = 0; half < 2; half++) {
    #pragma unroll
    for (int j = 0; j < 4; j++) {
      const int jj = half*4 + j;
      float4 e0 = dd4[4*jj+0], e1 = dd4[4*jj+1], e2 = dd4[4*jj+2], e3 = dd4[4*jj+3];
      float4 bb0 = bt4[(2*jj)^swr], bb1 = bt4[(2*jj+1)^swr];
      float4 cc0 = ct4[(2*jj)^swr], cc1 = ct4[(2*jj+1)^swr];
      h = fmaf(__expf(e0.x*A), h, e0.y*bb0.x); pr[8*j+0] = h*cc0.x;
      h = fmaf(__expf(e0.z*A), h, e0.w*bb0.y); pr[8*j+1] = h*cc0.y;
      h = fmaf(__expf(e1.x*A), h, e1.y*bb0.z); pr[8*j+2] = h*cc0.z;
      h = fmaf(__expf(e1.z*A), h, e1.w*bb0.w); pr[8*j+3] = h*cc0.w;
      h = fmaf(__expf(e2.x*A), h, e2.y*bb1.x); pr[8*j+4] = h*cc1.x;
      h = fmaf(__expf(e2.z*A), h, e2.w*bb1.y); pr[8*j+5] = h*cc1.y;
      h = fmaf(__expf(e3.x*A), h, e3.y*bb1.z); pr[8*j+6] = h*cc1.z;
      h = fmaf(__expf(e3.z*A), h, e3.w*bb1.w); pr[8*j+7] = h*cc1.w;
    }
    __syncthreads();
    {
      const int ch2 = tid & 3;
      const int tq  = tid >> 2;
      float a = 0.f;
      #pragma unroll
      for (int s2 = 0; s2 < 32; s2++) a += s_p[ch2*32 + s2][tq];
      ysbuf[(size_t)(b*TLEN + c*CLEN + half*32 + tq)*DI + d0 + ch2] = a;
    }
    __syncthreads();
  }
}

// ---------------- post: y=(ys+xi*Dp)*gate; out = base + y@Wout; optional fused LN ----------------
__global__ __launch_bounds__(256,4) void post_kernel(
    const float* __restrict__ ysbuf, const float* __restrict__ xibuf, const float* __restrict__ resgbuf,
    const float* __restrict__ Dp, const float* __restrict__ Wout,
    const float* __restrict__ zsrc, const float* __restrict__ pzsrc, int shift,
    float* __restrict__ outbuf, float* __restrict__ zdyn, float* __restrict__ predz,
    const float* __restrict__ gamma, const float* __restrict__ beta, int mode,
    int rstride, int roff)
{
  __shared__ float s_y[8*128];
  const int tid = threadIdx.x;
  const int b  = blockIdx.x >> 7;
  const int t0 = (blockIdx.x & 127) * 8;
  #pragma unroll
  for (int u = 0; u < 4; u++) {
    int i = tid + u*256;
    size_t gy = (size_t)(b*TLEN + t0)*DI + i;
    size_t gx = ((size_t)b*rstride + roff + t0)*DI + i;
    s_y[i] = (ysbuf[gy] + xibuf[gx]*Dp[i & 127]) * resgbuf[gx];
  }
  __syncthreads();
  #pragma unroll
  for (int u = 0; u < 2; u++) {
    int i = tid + u*256;
    int tau = i >> 6, c = i & 63;
    float a = 0.f;
    const float4* yy = (const float4*)&s_y[tau*128];
    #pragma unroll 4
    for (int k4 = 0; k4 < 32; k4++) {
      float4 vv = yy[k4];
      a = fmaf(vv.x, Wout[(k4*4+0)*64 + c], a);
      a = fmaf(vv.y, Wout[(k4*4+1)*64 + c], a);
      a = fmaf(vv.z, Wout[(k4*4+2)*64 + c], a);
      a = fmaf(vv.w, Wout[(k4*4+3)*64 + c], a);
    }
    size_t g = (size_t)(b*TLEN + t0 + tau)*DM + c;
    float base;
    if (zsrc) {
      int st = t0 + tau + shift;
      base = (st < TLEN) ? zsrc[(size_t)(b*TLEN + st)*DM + c] : pzsrc[(size_t)(b*4 + (st - TLEN))*DM + c];
    } else {
      base = outbuf[g];
    }
    float val = base + a;
    if (mode == 0) {
      outbuf[g] = val;
    } else {
      float sum = val;
      #pragma unroll
      for (int m = 1; m < 64; m <<= 1) sum += __shfl_xor(sum, m);
      float mean = sum * (1.f/64.f);
      float dv = val - mean;
      float vs = dv*dv;
      #pragma unroll
      for (int m = 1; m < 64; m <<= 1) vs += __shfl_xor(vs, m);
      float oln = dv * rsqrtf(vs*(1.f/64.f) + 1e-5f) * gamma[c] + beta[c];
      zdyn[g] = oln;
      if (t0 + tau == TLEN-1) predz[(size_t)(b*4 + 0)*DM + c] = oln;
    }
  }
}

// ---------------- standalone tiny_post (final pred slot) ----------------
__global__ __launch_bounds__(128) void tiny_post_kernel(
    const float* __restrict__ ysbuf, const float* __restrict__ xibuf, const float* __restrict__ resgbuf,
    const float* __restrict__ Dp, const float* __restrict__ Wout,
    float* __restrict__ predz, const float* __restrict__ gamma, const float* __restrict__ beta, int slot)
{
  __shared__ float s_y[128];
  const int tid = threadIdx.x;
  const int b = blockIdx.x;
  size_t g = (size_t)(b*TLEN + TLEN-1)*DI + tid;
  s_y[tid] = (ysbuf[g] + xibuf[g]*Dp[tid]) * resgbuf[g];
  __syncthreads();
  if (tid < 64) {
    float a = 0.f;
    #pragma unroll 4
    for (int k = 0; k < 128; k++) a = fmaf(s_y[k], Wout[k*64 + tid], a);
    float val = predz[(size_t)(b*4 + slot-1)*DM + tid] + a;
    float sum = val;
    #pragma unroll
    for (int m = 1; m < 64; m <<= 1) sum += __shfl_xor(sum, m);
    float mean = sum * (1.f/64.f);
    float dv = val - mean;
    float vs = dv*dv;
    #pragma unroll
    for (int m = 1; m < 64; m <<= 1) vs += __shfl_xor(vs, m);
    float oln = dv * rsqrtf(vs*(1.f/64.f) + 1e-5f) * gamma[tid] + beta[tid];
    predz[(size_t)(b*4 + slot)*DM + tid] = oln;
  }
}

extern "C" void kernel_launch(void* const* d_in, const int* in_sizes, int n_in,
                              void* d_out, int out_size, void* d_ws, size_t ws_size,
                              hipStream_t stream)
{
  (void)in_sizes; (void)n_in; (void)out_size; (void)ws_size;
  const float* x     = (const float*)d_in[0];
  const float* We1   = (const float*)d_in[1];
  const float* be1   = (const float*)d_in[2];
  const float* We2   = (const float*)d_in[3];
  const float* be2   = (const float*)d_in[4];
  const float* Wd1   = (const float*)d_in[5];
  const float* bd1   = (const float*)d_in[6];
  const float* Wd2   = (const float*)d_in[7];
  const float* bd2   = (const float*)d_in[8];
  const float* Win   = (const float*)d_in[9];
  const float* Wconv = (const float*)d_in[10];
  const float* bconv = (const float*)d_in[11];
  const float* Wxp   = (const float*)d_in[12];
  const float* Wdt   = (const float*)d_in[13];
  const float* bdt   = (const float*)d_in[14];
  const float* Alog  = (const float*)d_in[15];
  const float* Dp    = (const float*)d_in[16];
  const float* Wout  = (const float*)d_in[17];
  const float* gamma = (const float*)d_in[18];
  const float* beta  = (const float*)d_in[19];

  float* o      = (float*)d_out;
  float* x_rec  = o;                 // 8*1024*32
  float* x_dyn  = o + 262144;        // 8*1024*32
  float* x_pred = o + 524288;        // 8*4*32
  float* z      = o + 525312;        // 8*1024*64
  float* zdyn   = o + 1049600;       // 8*1024*64

  float* w     = (float*)d_ws;
  float* cur   = w;                            // 524288
  float* xi1   = cur  + 524288;                // 1048576
  float* resg1 = xi1  + 1048576;               // 1048576
  float2* dd1  = (float2*)(resg1 + 1048576);   // 2097152 floats
  float* Bb1   = resg1 + 1048576 + 2097152;    // 262144
  float* Cb1   = Bb1  + 262144;                // 262144
  float* ys    = Cb1  + 262144;                // 1048576
  float2* hc   = (float2*)(ys + 1048576);      // 1048576 floats
  float* predz = ys + 1048576 + 1048576;       // 2048
  float* xi0   = predz + 2048;                 // 1052672 (8*1028*128)
  float* resg0 = xi0  + 1052672;               // 1052672
  float2* dd0  = (float2*)(resg0 + 1052672);   // 2105344 floats
  float* Bb0   = resg0 + 1052672 + 2105344;    // 263168 (8*1028*32)
  float* Cb0   = Bb0  + 263168;                // 263168
  float* xz0   = Cb0  + 263168;                // 1052672 (xi-half of xz, global tokens)

  // block-0 / block-1 weights
  const float* Win0 = Win,               *Win1 = Win + 64*256;
  const float* Wcv0 = Wconv,             *Wcv1 = Wconv + 128*4;
  const float* bcv0 = bconv,             *bcv1 = bconv + 128;
  const float* Wxp0 = Wxp,               *Wxp1 = Wxp + 128*68;
  const float* Wdt0 = Wdt,               *Wdt1 = Wdt + 4*128;
  const float* bdt0 = bdt,               *bdt1 = bdt + 128;
  const float* Al0  = Alog,              *Al1  = Alog + 128*32;
  const float* Dp0  = Dp,                *Dp1  = Dp + 128;
  const float* Wo0  = Wout,              *Wo1  = Wout + 128*64;

  // encoder + reconstruction decoder (fused)
  enc_xrec_kernel<<<dim3(512), dim3(256), 0, stream>>>(x, We1, be1, We2, be2, Wd1, bd1, Wd2, bd2, z, x_rec);

  // pre(i=0) ONCE over global z tokens (pass-0 padding semantics), storing xz xi-half
  pre_kernel<<<dim3(1024), dim3(256), 0, stream>>>(cur, z, predz, 0,
                                                   Win0, Wcv0, bcv0, Wxp0, Wdt0, bdt0,
                                                   xi0, resg0, dd0, Bb0, Cb0, xz0, GEXT);

  for (int p = 0; p < 4; p++) {
    if (p >= 1) {
      // patch pre(i=0) tokens {p,p+1,p+2, 1023+p}; for p>=2 also performs tiny_post of pass p-1
      patch_kernel<<<dim3(8), dim3(128*2), 0, stream>>>(p, (p >= 2) ? 1 : 0,
          ys, xi1, resg1, Dp1, Wo1, gamma, beta, predz,
          xz0, Win0, Wcv0, bcv0, Wxp0, Wdt0, bdt0,
          xi0, resg0, dd0, Bb0, Cb0);
    }
    // ---- block i=0 (shared pre buffers, window at offset p) ----
    scan1_kernel<<<dim3(4096), dim3(128), 0, stream>>>(dd0, Bb0, Al0, hc, GEXT, p);
    scan3_kernel<<<dim3(4096), dim3(128), 0, stream>>>(dd0, Bb0, Cb0, Al0, hc, ys, -1, GEXT, p);
    post_kernel<<<dim3(1024), dim3(256), 0, stream>>>(ys, xi0, resg0, Dp0, Wo0,
                                                      z, predz, p, cur,
                                                      (float*)nullptr, (float*)nullptr,
                                                      (const float*)nullptr, (const float*)nullptr, 0,
                                                      GEXT, p);
    // ---- block i=1 (pass-local) ----
    pre_kernel<<<dim3(1024), dim3(256), 0, stream>>>(cur, (const float*)nullptr, (const float*)nullptr, 0,
                                                     Win1, Wcv1, bcv1, Wxp1, Wdt1, bdt1,
                                                     xi1, resg1, dd1, Bb1, Cb1, (float*)nullptr, TLEN);
    scan1_kernel<<<dim3(4096), dim3(128), 0, stream>>>(dd1, Bb1, Al1, hc, TLEN, 0);
    if (p == 0) {
      scan3_kernel<<<dim3(4096), dim3(128), 0, stream>>>(dd1, Bb1, Cb1, Al1, hc, ys, -1, TLEN, 0);
      post_kernel<<<dim3(1024), dim3(256), 0, stream>>>(ys, xi1, resg1, Dp1, Wo1,
                                                        (const float*)nullptr, (const float*)nullptr, 0, cur,
                                                        zdyn, predz, gamma, beta, 1, TLEN, 0);
    } else {
      scan3_kernel<<<dim3(256), dim3(128), 0, stream>>>(dd1, Bb1, Cb1, Al1, hc, ys, 15, TLEN, 0);
      if (p == 3)
        tiny_post_kernel<<<dim3(8), dim3(128), 0, stream>>>(ys, xi1, resg1, Dp1, Wo1,
                                                            predz, gamma, beta, 3);
    }
  }

  // x_dyn = dec(zdyn) + x_pred = dec(predz)
  dec2_kernel<<<dim3(514), dim3(256), 0, stream>>>(zdyn, predz, Wd1, bd1, Wd2, bd2, x_dyn, x_pred);
}